// Round 17
// baseline (742.316 us; speedup 1.0000x reference)
//
#include <hip/hip_runtime.h>
#include <hip/hip_cooperative_groups.h>

namespace cg = cooperative_groups;

#define NN 50000
#define NE 800000
#define NB 512
#define DIN 128
#define DD2 200
#define C1 100
#define C2 20
#define DHH 64
#define HH1 128
#define HH2 32
#define KD 201
#define KDP 204
#define NU 2688
#define NCT 7
#define NTILE 3125
#define GB1 782     // gemm1 jobs (4 tiles each)
#define FCB 672     // fc1V jobs
#define FPB 3125    // fill jobs
#define J2 4688     // phase-2 job count: fill slots = 4688 - 1563 = 3125 exactly
#define PS1 128
#define SLOT 64
#define OVFCAP 8192

typedef short sh8 __attribute__((ext_vector_type(8)));
typedef float f32x4 __attribute__((ext_vector_type(4)));

__device__ __forceinline__ unsigned short f2bf(float x) {
    unsigned u = __float_as_uint(x);
    unsigned r = (u + 0x7fffu + ((u >> 16) & 1u)) >> 16;
    return (unsigned short)r;
}
__device__ __forceinline__ float bf_lo(unsigned u) { return __uint_as_float(u << 16); }
__device__ __forceinline__ float bf_hi(unsigned u) { return __uint_as_float(u & 0xffff0000u); }

struct Params {
    const float* feat; const float* desc2d;
    const float* gc1W; const float* gc1b; const float* gc2W; const float* gc2b;
    const float* pgW; const float* pgb; const float* p2W; const float* p2b;
    const float* W2; const float* fc1W; const float* fc2W;
    const float* fc3W; const float* fc3b;
    const float* bn1g; const float* bn1b; const float* bn2g; const float* bn2b;
    const int* src; const int* dst; const int* gid;
    unsigned char* t1f8; unsigned* h1b; unsigned* t2b;
    int* cnt; int* pos; int* epad; int2* ovf; int* ovfc;
    unsigned short* Bf; float* V; float* hgs; float* o1; float* o2;
    float* out;
};

__global__ __launch_bounds__(256, 4) void k_mega(Params p) {
    __shared__ __align__(16) char smem[28672];
    cg::grid_group grid = cg::this_grid();
    const int tid = threadIdx.x;
    const int bid = blockIdx.x;
    const int gdim = gridDim.x;

    // ================= P1: init (pack Bf, zero cnt/hgs/ovfc) =================
    {
        const int gt = bid * 256 + tid, gs = gdim * 256;
        for (int i = gt; i < NN; i += gs) {
            p.cnt[i] = 0;
            if (i < NCT * 4 * 64) {
                int lane = i & 63, kc = (i >> 6) & 3, ct = i >> 8;
                int col = ct * 16 + (lane & 15);
                int k0 = kc * 32 + (lane >> 4) * 8;
                unsigned short* outp = p.Bf + (size_t)i * 8;
                #pragma unroll
                for (int e = 0; e < 8; ++e) {
                    float v = (col < C1) ? p.gc1W[(k0 + e) * C1 + col] : 0.f;
                    outp[e] = f2bf(v);
                }
            }
            if (i < NB * C2) p.hgs[i] = 0.f;
            if (i == 0) *p.ovfc = 0;
        }
    }
    grid.sync();

    // ================= P2: gemm1 || fillpos || fc1V (interleaved) =================
    {
        int lstate = -1;
        for (int j = bid; j < J2; j += gdim) {
            if (j % 3 == 0) {
                int cj = j / 3;
                if (cj < GB1) {
                    // ---- gemm1 (MFMA, fp8 out) ----
                    sh8* sB = (sh8*)smem;
                    if (lstate != 0) {
                        __syncthreads();
                        const uint4* srcp = (const uint4*)p.Bf;
                        uint4* dstp = (uint4*)smem;
                        for (int i = tid; i < NCT * 4 * 64; i += 256) dstp[i] = srcp[i];
                        lstate = 0;
                    }
                    __syncthreads();
                    const int w = tid >> 6, lane = tid & 63;
                    const int ri = lane & 15, kg = lane >> 4;
                    int tile = cj * 4 + w;
                    if (tile < NTILE) {
                        const int n = tile * 16 + ri;
                        f32x4 acc[NCT];
                        #pragma unroll
                        for (int ct = 0; ct < NCT; ++ct) acc[ct] = (f32x4){0.f, 0.f, 0.f, 0.f};
                        #pragma unroll
                        for (int kc = 0; kc < 4; ++kc) {
                            const float* ap = p.feat + (size_t)n * DIN + kc * 32 + kg * 8;
                            float4 a0 = *(const float4*)ap;
                            float4 a1 = *(const float4*)(ap + 4);
                            union { sh8 v; unsigned short u[8]; } af;
                            af.u[0] = f2bf(a0.x); af.u[1] = f2bf(a0.y);
                            af.u[2] = f2bf(a0.z); af.u[3] = f2bf(a0.w);
                            af.u[4] = f2bf(a1.x); af.u[5] = f2bf(a1.y);
                            af.u[6] = f2bf(a1.z); af.u[7] = f2bf(a1.w);
                            #pragma unroll
                            for (int ct = 0; ct < NCT; ++ct)
                                acc[ct] = __builtin_amdgcn_mfma_f32_16x16x32_bf16(
                                    af.v, sB[(ct * 4 + kc) * 64 + lane], acc[ct], 0, 0, 0);
                        }
                        const int rbase = tile * 16 + kg * 4;
                        #pragma unroll
                        for (int ct = 0; ct < NCT; ++ct) {
                            int col = ct * 16 + ri;
                            if (col < C1) {
                                #pragma unroll
                                for (int r = 0; r < 4; ++r) {
                                    int pk = __builtin_amdgcn_cvt_pk_fp8_f32(acc[ct][r], acc[ct][r], 0, false);
                                    p.t1f8[(size_t)(rbase + r) * PS1 + col] = (unsigned char)(pk & 0xFF);
                                }
                            }
                        }
                    }
                } else if (cj < GB1 + FCB) {
                    // ---- fc1V ----
                    int fid = cj - GB1;
                    float (*S)[KDP] = (float(*)[KDP])smem;
                    const int i = fid / 32;
                    const int rem = fid % 32;
                    const int bt = rem >> 1, half = rem & 1;
                    __syncthreads();
                    for (int idx = tid; idx < 32 * 50; idx += 256) {
                        int r = idx / 50, c4 = idx % 50;
                        *(float4*)&S[r][c4 * 4] =
                            *(const float4*)(p.desc2d + (size_t)(bt * 32 + r) * DD2 + c4 * 4);
                    }
                    __syncthreads();
                    const int c = tid & 31, rg = tid >> 5;
                    float acc[4][2];
                    #pragma unroll
                    for (int r = 0; r < 4; ++r) { acc[r][0] = 0.f; acc[r][1] = 0.f; }
                    const float* Wb = p.fc1W + (size_t)i * (KD * HH1) + half * 64 + c;
                    for (int k = 0; k < 200; k += 4) {
                        const float* Wk = Wb + (size_t)k * HH1;
                        float w0[2], w1[2], w2[2], w3[2];
                        #pragma unroll
                        for (int m = 0; m < 2; ++m) {
                            w0[m] = Wk[32 * m];
                            w1[m] = Wk[HH1 + 32 * m];
                            w2[m] = Wk[2 * HH1 + 32 * m];
                            w3[m] = Wk[3 * HH1 + 32 * m];
                        }
                        #pragma unroll
                        for (int r = 0; r < 4; ++r) {
                            float4 a4 = *(const float4*)&S[rg * 4 + r][k];
                            #pragma unroll
                            for (int m = 0; m < 2; ++m)
                                acc[r][m] += a4.x * w0[m] + a4.y * w1[m] + a4.z * w2[m] + a4.w * w3[m];
                        }
                    }
                    #pragma unroll
                    for (int r = 0; r < 4; ++r) {
                        int b = bt * 32 + rg * 4 + r;
                        float* Vr = p.V + (size_t)b * NU + i * HH1 + half * 64 + c;
                        Vr[0] = acc[r][0];
                        Vr[32] = acc[r][1];
                    }
                    lstate = 1;
                }
            } else {
                int fj = j - j / 3 - 1;
                if (fj < FPB) {
                    int e = fj * 256 + tid;
                    if (e < NE) p.pos[e] = atomicAdd(&p.cnt[p.dst[e]], 1);
                }
            }
        }
    }
    grid.sync();

    // ================= P3: scatter into padded slots =================
    for (int job = bid; job < FPB; job += gdim) {
        int e = job * 256 + tid;
        if (e < NE) {
            int d = p.dst[e], pp = p.pos[e], s = p.src[e];
            if (pp < SLOT) {
                p.epad[(size_t)d * SLOT + pp] = s;
            } else {
                int o = atomicAdd(p.ovfc, 1);
                if (o < OVFCAP) p.ovf[o] = make_int2(d, s);
            }
        }
    }
    grid.sync();

    // ================= P4: agg1 (fp8 gather-mean + bias + relu -> h1b) =================
    for (int job = bid; job < 12500; job += gdim) {
        const int w = tid >> 6, l = tid & 63;
        const int n = job * 4 + w;
        if (n < NN && l < 50) {
            const int deg = p.cnt[n];
            const int m = deg < SLOT ? deg : SLOT;
            const int* ep = p.epad + (size_t)n * SLOT;
            const int co = 2 * l;
            float acc0 = 0.f, acc1 = 0.f;
            int e = 0;
            for (; e + 7 < m; e += 8) {
                int s0 = ep[e],     s1 = ep[e + 1], s2 = ep[e + 2], s3 = ep[e + 3];
                int s4 = ep[e + 4], s5 = ep[e + 5], s6 = ep[e + 6], s7 = ep[e + 7];
                int u0 = *(const unsigned short*)(p.t1f8 + (size_t)s0 * PS1 + co);
                int u1 = *(const unsigned short*)(p.t1f8 + (size_t)s1 * PS1 + co);
                int u2 = *(const unsigned short*)(p.t1f8 + (size_t)s2 * PS1 + co);
                int u3 = *(const unsigned short*)(p.t1f8 + (size_t)s3 * PS1 + co);
                int u4 = *(const unsigned short*)(p.t1f8 + (size_t)s4 * PS1 + co);
                int u5 = *(const unsigned short*)(p.t1f8 + (size_t)s5 * PS1 + co);
                int u6 = *(const unsigned short*)(p.t1f8 + (size_t)s6 * PS1 + co);
                int u7 = *(const unsigned short*)(p.t1f8 + (size_t)s7 * PS1 + co);
                acc0 += __builtin_amdgcn_cvt_f32_fp8(u0, 0); acc1 += __builtin_amdgcn_cvt_f32_fp8(u0, 1);
                acc0 += __builtin_amdgcn_cvt_f32_fp8(u1, 0); acc1 += __builtin_amdgcn_cvt_f32_fp8(u1, 1);
                acc0 += __builtin_amdgcn_cvt_f32_fp8(u2, 0); acc1 += __builtin_amdgcn_cvt_f32_fp8(u2, 1);
                acc0 += __builtin_amdgcn_cvt_f32_fp8(u3, 0); acc1 += __builtin_amdgcn_cvt_f32_fp8(u3, 1);
                acc0 += __builtin_amdgcn_cvt_f32_fp8(u4, 0); acc1 += __builtin_amdgcn_cvt_f32_fp8(u4, 1);
                acc0 += __builtin_amdgcn_cvt_f32_fp8(u5, 0); acc1 += __builtin_amdgcn_cvt_f32_fp8(u5, 1);
                acc0 += __builtin_amdgcn_cvt_f32_fp8(u6, 0); acc1 += __builtin_amdgcn_cvt_f32_fp8(u6, 1);
                acc0 += __builtin_amdgcn_cvt_f32_fp8(u7, 0); acc1 += __builtin_amdgcn_cvt_f32_fp8(u7, 1);
            }
            for (; e < m; ++e) {
                int u = *(const unsigned short*)(p.t1f8 + (size_t)ep[e] * PS1 + co);
                acc0 += __builtin_amdgcn_cvt_f32_fp8(u, 0);
                acc1 += __builtin_amdgcn_cvt_f32_fp8(u, 1);
            }
            if (deg > SLOT) {
                int novf = *p.ovfc; novf = novf < OVFCAP ? novf : OVFCAP;
                for (int j2 = 0; j2 < novf; ++j2) {
                    int2 pr = p.ovf[j2];
                    if (pr.x == n) {
                        int u = *(const unsigned short*)(p.t1f8 + (size_t)pr.y * PS1 + co);
                        acc0 += __builtin_amdgcn_cvt_f32_fp8(u, 0);
                        acc1 += __builtin_amdgcn_cvt_f32_fp8(u, 1);
                    }
                }
            }
            float d = (float)(deg > 0 ? deg : 1);
            float v0 = fmaxf(acc0 / d + p.gc1b[co], 0.f);
            float v1 = fmaxf(acc1 / d + p.gc1b[co + 1], 0.f);
            p.h1b[(size_t)n * 50 + l] = (unsigned)f2bf(v0) | ((unsigned)f2bf(v1) << 16);
        }
    }
    grid.sync();

    // ================= P5: gemm2 (t2b = h1 @ gc2W, packed bf16) =================
    {
        float* sW = (float*)smem;                        // 2000 floats
        float (*sr)[C1] = (float(*)[C1])(smem + 8192);   // [12][100]
        float (*sc)[C2] = (float(*)[C2])(smem + 13312);  // [12][20]
        __syncthreads();
        for (int idx = tid; idx < C1 * C2; idx += 256) sW[idx] = p.gc2W[idx];
        for (int job = bid; job < 4167; job += gdim) {
            __syncthreads();
            int n0 = job * 12;
            for (int idx = tid; idx < 12 * 50; idx += 256) {
                int r = idx / 50, c = idx % 50;
                int n = n0 + r;
                unsigned u = (n < NN) ? p.h1b[(size_t)n * 50 + c] : 0u;
                sr[r][2 * c] = bf_lo(u);
                sr[r][2 * c + 1] = bf_hi(u);
            }
            __syncthreads();
            int ln = tid / C2, j = tid % C2;
            if (ln < 12) {
                float acc = 0.f;
                #pragma unroll 4
                for (int k = 0; k < C1; ++k) acc += sr[ln][k] * sW[k * C2 + j];
                sc[ln][j] = acc;
            }
            __syncthreads();
            for (int idx = tid; idx < 12 * 10; idx += 256) {
                int r = idx / 10, jp = idx % 10;
                int n = n0 + r;
                if (n < NN)
                    p.t2b[(size_t)n * 10 + jp] =
                        (unsigned)f2bf(sc[r][2 * jp]) | ((unsigned)f2bf(sc[r][2 * jp + 1]) << 16);
            }
        }
    }
    grid.sync();

    // ================= P6: agg2 + graph pool =================
    for (int job = bid; job < 4167; job += gdim) {
        int ln = tid / C2, c = tid % C2;
        if (ln < 12) {
            int n = job * 12 + ln;
            if (n < NN) {
                const int deg = p.cnt[n];
                const int m = deg < SLOT ? deg : SLOT;
                const int* ep = p.epad + (size_t)n * SLOT;
                const int jp = c >> 1, hi = c & 1;
                float acc = 0.f;
                int e = 0;
                for (; e + 3 < m; e += 4) {
                    int s0 = ep[e], s1 = ep[e + 1], s2 = ep[e + 2], s3 = ep[e + 3];
                    unsigned u0 = p.t2b[(size_t)s0 * 10 + jp];
                    unsigned u1 = p.t2b[(size_t)s1 * 10 + jp];
                    unsigned u2 = p.t2b[(size_t)s2 * 10 + jp];
                    unsigned u3 = p.t2b[(size_t)s3 * 10 + jp];
                    acc += hi ? bf_hi(u0) : bf_lo(u0);
                    acc += hi ? bf_hi(u1) : bf_lo(u1);
                    acc += hi ? bf_hi(u2) : bf_lo(u2);
                    acc += hi ? bf_hi(u3) : bf_lo(u3);
                }
                for (; e < m; ++e) {
                    unsigned u = p.t2b[(size_t)ep[e] * 10 + jp];
                    acc += hi ? bf_hi(u) : bf_lo(u);
                }
                if (deg > SLOT) {
                    int novf = *p.ovfc; novf = novf < OVFCAP ? novf : OVFCAP;
                    for (int j2 = 0; j2 < novf; ++j2) {
                        int2 pr = p.ovf[j2];
                        if (pr.x == n) {
                            unsigned u = p.t2b[(size_t)pr.y * 10 + jp];
                            acc += hi ? bf_hi(u) : bf_lo(u);
                        }
                    }
                }
                float d = (float)(deg > 0 ? deg : 1);
                float v = fmaxf(acc / d + p.gc2b[c], 0.f);
                atomicAdd(&p.hgs[p.gid[n] * C2 + c], v);
            }
        }
    }
    grid.sync();

    // ================= P7: head + fc1b (2 graphs per block) =================
    {
        float* shg = (float*)smem;        // [2][C2]
        float* sg  = shg + 2 * C2;        // [2][DHH]
        float* sa  = sg + 2 * DHH;        // [2]
        for (int job = bid; job < NB / 2; job += gdim) {
            __syncthreads();
            const int w = tid >> 7, t2 = tid & 127;
            const int b = job * 2 + w;
            if (t2 < C2) {
                int lo = 0, hi = NN;
                while (lo < hi) { int m = (lo + hi) >> 1; if (p.gid[m] < b) lo = m + 1; else hi = m; }
                int lo2 = lo, hi2 = NN;
                while (lo2 < hi2) { int m = (lo2 + hi2) >> 1; if (p.gid[m] < b + 1) lo2 = m + 1; else hi2 = m; }
                float dcnt = (float)(lo2 - lo);
                if (dcnt < 1.f) dcnt = 1.f;
                shg[w * C2 + t2] = p.hgs[b * C2 + t2] / dcnt;
            }
            __syncthreads();
            float hdj = 0.f;
            if (t2 < DHH) {
                float hgj = p.pgb[t2];
                #pragma unroll
                for (int k = 0; k < C2; ++k) hgj += shg[w * C2 + k] * p.pgW[k * DHH + t2];
                hdj = p.p2b[t2];
                #pragma unroll 4
                for (int k = 0; k < DD2; ++k) hdj += p.desc2d[b * DD2 + k] * p.p2W[k * DHH + t2];
                sg[w * DHH + t2] = hgj;
            }
            __syncthreads();
            if (t2 < DHH) {
                float tj = 0.f;
                #pragma unroll 4
                for (int k = 0; k < DHH; ++k) tj += sg[w * DHH + k] * p.W2[k * DHH + t2];
                float v = tj * hdj;
                #pragma unroll
                for (int off = 32; off; off >>= 1) v += __shfl_xor(v, off, 64);
                if (t2 == 0) sa[w] = 1.f / (1.f + expf(-v));
            }
            __syncthreads();
            const float* Vb = p.V + (size_t)b * NU + t2;
            const float* WL = p.fc1W + (size_t)200 * HH1 + t2;
            float sv = Vb[20 * HH1];
            float sw = WL[(size_t)20 * KD * HH1];
            #pragma unroll
            for (int i = 0; i < 20; ++i) {
                float h = shg[w * C2 + i];
                sv += h * Vb[i * HH1];
                sw += h * WL[(size_t)i * KD * HH1];
            }
            p.o1[b * HH1 + t2] = sa[w] * sv + sw;
        }
    }
    grid.sync();

    // ================= P8: fc2 with in-block bn1 stats =================
    {
        float* rbuf = (float*)smem;       // 128
        float* part = rbuf + 128;         // [4][32]
        for (int job = bid; job < 128; job += gdim) {
            float scale = 0.f, shift = 0.f;
            if (tid < HH1) {
                float s = 0.f, s2 = 0.f;
                for (int b = 0; b < NB; ++b) {
                    float v = p.o1[b * HH1 + tid];
                    s += v; s2 += v * v;
                }
                float mu = s / NB;
                float rstd = rsqrtf(s2 / NB - mu * mu + 1e-5f);
                scale = rstd * p.bn1g[tid];
                shift = p.bn1b[tid] - mu * scale;
            }
            const int m = tid & 31, pq = (tid >> 5) & 3;
            for (int q = 0; q < 4; ++q) {
                int b = job * 4 + q;
                float v = (tid < HH1) ? p.o1[b * HH1 + tid] : 0.f;
                __syncthreads();
                if (tid < HH1) rbuf[tid] = fmaxf(v * scale + shift, 0.f);
                __syncthreads();
                if (tid < HH1) {
                    float acc = 0.f;
                    #pragma unroll 4
                    for (int j = pq * 32; j < pq * 32 + 32; ++j) acc += rbuf[j] * p.fc2W[j * HH2 + m];
                    part[pq * 32 + m] = acc;
                }
                __syncthreads();
                if (tid < HH2)
                    p.o2[b * HH2 + tid] = part[tid] + part[32 + tid] + part[64 + tid] + part[96 + tid];
                __syncthreads();
            }
        }
    }
    grid.sync();

    // ================= P9: bn2 + relu + fc3 (block 0) =================
    if (bid == 0) {
        float* ps  = (float*)smem;        // [8][32]
        float* ps2 = ps + 256;
        float* sscale = ps2 + 256;
        float* sshift = sscale + 32;
        const int gq = tid >> 5, m = tid & 31;
        float s = 0.f, s2 = 0.f;
        for (int rr = 0; rr < 64; ++rr) {
            float v = p.o2[(gq * 64 + rr) * HH2 + m];
            s += v; s2 += v * v;
        }
        ps[gq * 32 + m] = s; ps2[gq * 32 + m] = s2;
        __syncthreads();
        if (tid < HH2) {
            float ts = 0.f, ts2 = 0.f;
            #pragma unroll
            for (int q = 0; q < 8; ++q) { ts += ps[q * 32 + tid]; ts2 += ps2[q * 32 + tid]; }
            float mu = ts / NB;
            float rstd = rsqrtf(ts2 / NB - mu * mu + 1e-5f);
            float scale = rstd * p.bn2g[tid];
            sscale[tid] = scale;
            sshift[tid] = p.bn2b[tid] - mu * scale;
        }
        __syncthreads();
        for (int b = tid; b < NB; b += 256) {
            float acc = p.fc3b[0];
            #pragma unroll 4
            for (int mm = 0; mm < HH2; ++mm) {
                float v = p.o2[b * HH2 + mm];
                acc += fmaxf(v * sscale[mm] + sshift[mm], 0.f) * p.fc3W[mm];
            }
            p.out[b] = acc;
        }
    }
}

extern "C" void kernel_launch(void* const* d_in, const int* in_sizes, int n_in,
                              void* d_out, int out_size, void* d_ws, size_t ws_size,
                              hipStream_t stream) {
    char* ws = (char*)d_ws;
    size_t off = 0;
    auto alloc = [&](size_t nb) {
        void* pp = ws + off;
        off = (off + nb + 255) & ~(size_t)255;
        return pp;
    };
    Params p;
    p.feat   = (const float*)d_in[0];
    p.desc2d = (const float*)d_in[1];
    p.gc1W = (const float*)d_in[3];
    p.gc1b = (const float*)d_in[4];
    p.gc2W = (const float*)d_in[5];
    p.gc2b = (const float*)d_in[6];
    p.pgW  = (const float*)d_in[7];
    p.pgb  = (const float*)d_in[8];
    p.p2W  = (const float*)d_in[9];
    p.p2b  = (const float*)d_in[10];
    p.W2   = (const float*)d_in[11];
    p.fc1W = (const float*)d_in[12];
    p.fc2W = (const float*)d_in[14];
    p.fc3W = (const float*)d_in[16];
    p.fc3b = (const float*)d_in[17];
    p.bn1g = (const float*)d_in[18];
    p.bn1b = (const float*)d_in[19];
    p.bn2g = (const float*)d_in[20];
    p.bn2b = (const float*)d_in[21];
    p.src = (const int*)d_in[22];
    p.dst = (const int*)d_in[23];
    p.gid = (const int*)d_in[24];
    p.out = (float*)d_out;

    p.t1f8 = (unsigned char*)alloc((size_t)NN * PS1);
    p.h1b  = (unsigned*)alloc((size_t)NN * 50 * 4);
    p.t2b  = (unsigned*)alloc((size_t)NN * 10 * 4);
    p.cnt  = (int*)alloc((size_t)NN * 4);
    p.pos  = (int*)alloc((size_t)NE * 4);
    p.epad = (int*)alloc((size_t)NN * SLOT * 4);
    p.ovf  = (int2*)alloc((size_t)OVFCAP * 8);
    p.ovfc = (int*)alloc(256);
    p.Bf   = (unsigned short*)alloc((size_t)NCT * 4 * 64 * 16);
    p.V    = (float*)alloc((size_t)NB * NU * 4);
    p.hgs  = (float*)alloc((size_t)NB * C2 * 4);
    p.o1   = (float*)alloc((size_t)NB * HH1 * 4);
    p.o2   = (float*)alloc((size_t)NB * HH2 * 4);

    int maxb = 0;
    hipOccupancyMaxActiveBlocksPerMultiprocessor(&maxb, k_mega, 256, 0);
    if (maxb < 1) maxb = 1;
    long long grid = (long long)maxb * 256;
    if (grid > 2048) grid = 2048;

    void* args[] = { (void*)&p };
    hipLaunchCooperativeKernel((void*)k_mega, dim3((unsigned)grid), dim3(256),
                               args, 0, stream);
}

// Round 18
// 203.949 us; speedup vs baseline: 3.6397x; 3.6397x over previous
//
#include <hip/hip_runtime.h>

#define NN 50000
#define NE 800000
#define NB 512
#define DIN 128
#define DD2 200
#define C1 100
#define C2 20
#define DHH 64
#define HH1 128
#define HH2 32
#define KD 201      // fusion inner dim per i (200 + 1)
#define KDP 204     // padded LDS row stride
#define NU 2688     // 21 * 128
#define SCB 196     // init blocks
#define NCT 7       // col tiles of 16 covering 100
#define NTILE 3125  // 50000 / 16 row tiles
#define GB1 782     // gemm1 blocks in k_front
#define FPB 3125    // fill blocks in k_front
#define FCB 672     // fc1V blocks in k_front
#define PS1 128     // t1 fp8 row stride (bytes)
#define SLOT 64     // padded edge slots per node
#define OVFCAP 8192

typedef short sh8 __attribute__((ext_vector_type(8)));
typedef float f32x4 __attribute__((ext_vector_type(4)));

__device__ __forceinline__ unsigned short f2bf(float x) {
    unsigned u = __float_as_uint(x);
    unsigned r = (u + 0x7fffu + ((u >> 16) & 1u)) >> 16;   // RNE
    return (unsigned short)r;
}
__device__ __forceinline__ float bf_lo(unsigned u) { return __uint_as_float(u << 16); }
__device__ __forceinline__ float bf_hi(unsigned u) { return __uint_as_float(u & 0xffff0000u); }

// ---------------- init: pack gc1_W into B-fragments + zero cnt/hgs/ovfc/done ----------------
__global__ void k_packB_init(const float* __restrict__ W, unsigned short* __restrict__ Bf,
                             int* __restrict__ cnt, float* __restrict__ hgs,
                             int* __restrict__ ovfc, int* __restrict__ done) {
    int idx = blockIdx.x * 256 + threadIdx.x;
    if (idx < NCT * 4 * 64) {
        int lane = idx & 63;
        int kc = (idx >> 6) & 3;
        int ct = idx >> 8;
        int col = ct * 16 + (lane & 15);
        int k0 = kc * 32 + (lane >> 4) * 8;
        unsigned short* outp = Bf + (size_t)idx * 8;
        #pragma unroll
        for (int e = 0; e < 8; ++e) {
            float v = (col < C1) ? W[(k0 + e) * C1 + col] : 0.f;
            outp[e] = f2bf(v);
        }
    }
    if (idx < NN) cnt[idx] = 0;
    if (idx < NB * C2) hgs[idx] = 0.f;
    if (idx == 0) { *ovfc = 0; *done = 0; }
}

// ---------------- fused front: fillpos (first) || gemm1 (MFMA, fp8-out) || fc1V GEMM ----------------
__global__ __launch_bounds__(256) void k_front(const float* __restrict__ feat,
                                               const unsigned short* __restrict__ Bf,
                                               unsigned char* __restrict__ t1f8,
                                               const int* __restrict__ dst,
                                               int* __restrict__ cnt,
                                               int* __restrict__ pos,
                                               const float* __restrict__ desc2d,
                                               const float* __restrict__ W1,
                                               float* __restrict__ V) {
    __shared__ float smem[7168];         // 28 KB, shared by gemm1 (sB) and fc1V (S)
    const int tid = threadIdx.x;

    if (blockIdx.x < FPB) {
        // ---- fillpos: one atomic pass, coalesced pos write. Runs from t=0. ----
        int e = blockIdx.x * 256 + tid;
        if (e < NE) pos[e] = atomicAdd(&cnt[dst[e]], 1);
        return;
    }

    if (blockIdx.x < FPB + GB1) {
        // ---- gemm1 via MFMA ----
        const int cj = blockIdx.x - FPB;
        sh8* sB = (sh8*)smem;            // [NCT][4][64]
        {
            const uint4* srcp = (const uint4*)Bf;
            uint4* dstp = (uint4*)smem;
            for (int i = tid; i < NCT * 4 * 64; i += 256) dstp[i] = srcp[i];
        }
        __syncthreads();
        const int w = tid >> 6, lane = tid & 63;
        const int ri = lane & 15;
        const int kg = lane >> 4;
        int tile = cj * 4 + w;
        if (tile < NTILE) {
            const int n = tile * 16 + ri;
            f32x4 acc[NCT];
            #pragma unroll
            for (int ct = 0; ct < NCT; ++ct) acc[ct] = (f32x4){0.f, 0.f, 0.f, 0.f};
            #pragma unroll
            for (int kc = 0; kc < 4; ++kc) {
                const float* ap = feat + (size_t)n * DIN + kc * 32 + kg * 8;
                float4 a0 = *(const float4*)ap;
                float4 a1 = *(const float4*)(ap + 4);
                union { sh8 v; unsigned short u[8]; } af;
                af.u[0] = f2bf(a0.x); af.u[1] = f2bf(a0.y);
                af.u[2] = f2bf(a0.z); af.u[3] = f2bf(a0.w);
                af.u[4] = f2bf(a1.x); af.u[5] = f2bf(a1.y);
                af.u[6] = f2bf(a1.z); af.u[7] = f2bf(a1.w);
                #pragma unroll
                for (int ct = 0; ct < NCT; ++ct)
                    acc[ct] = __builtin_amdgcn_mfma_f32_16x16x32_bf16(
                        af.v, sB[(ct * 4 + kc) * 64 + lane], acc[ct], 0, 0, 0);
            }
            const int rbase = tile * 16 + kg * 4;
            #pragma unroll
            for (int ct = 0; ct < NCT; ++ct) {
                int col = ct * 16 + ri;
                if (col < C1) {
                    #pragma unroll
                    for (int r = 0; r < 4; ++r) {
                        int pk = __builtin_amdgcn_cvt_pk_fp8_f32(acc[ct][r], acc[ct][r], 0, false);
                        t1f8[(size_t)(rbase + r) * PS1 + col] = (unsigned char)(pk & 0xFF);
                    }
                }
            }
        }
        return;
    }

    // ---- fc1V: V[b][i*128+j] = sum_{k<200} desc2d[b][k] * W1[(i*201+k)*128+j] ----
    {
        float (*S)[KDP] = (float(*)[KDP])smem;   // [32][204]
        int fid = blockIdx.x - FPB - GB1;        // 0..671
        const int i = fid / 32;
        const int rem = fid % 32;
        const int bt = rem >> 1;
        const int half = rem & 1;
        for (int idx = tid; idx < 32 * 50; idx += 256) {
            int r = idx / 50, c4 = idx % 50;
            *(float4*)&S[r][c4 * 4] =
                *(const float4*)(desc2d + (size_t)(bt * 32 + r) * DD2 + c4 * 4);
        }
        __syncthreads();
        const int c = tid & 31;
        const int rg = tid >> 5;
        float acc[4][2];
        #pragma unroll
        for (int r = 0; r < 4; ++r) { acc[r][0] = 0.f; acc[r][1] = 0.f; }
        const float* Wb = W1 + (size_t)i * (KD * HH1) + half * 64 + c;
        for (int k = 0; k < 200; k += 4) {
            const float* Wk = Wb + (size_t)k * HH1;
            float w0[2], w1[2], w2[2], w3[2];
            #pragma unroll
            for (int m = 0; m < 2; ++m) {
                w0[m] = Wk[32 * m];
                w1[m] = Wk[HH1 + 32 * m];
                w2[m] = Wk[2 * HH1 + 32 * m];
                w3[m] = Wk[3 * HH1 + 32 * m];
            }
            #pragma unroll
            for (int r = 0; r < 4; ++r) {
                float4 a4 = *(const float4*)&S[rg * 4 + r][k];
                #pragma unroll
                for (int m = 0; m < 2; ++m)
                    acc[r][m] += a4.x * w0[m] + a4.y * w1[m] + a4.z * w2[m] + a4.w * w3[m];
            }
        }
        #pragma unroll
        for (int r = 0; r < 4; ++r) {
            int b = bt * 32 + rg * 4 + r;
            float* Vr = V + (size_t)b * NU + i * HH1 + half * 64 + c;
            Vr[0] = acc[r][0];
            Vr[32] = acc[r][1];
        }
    }
}

// ---------------- scatter src into padded slots (no atomics, no scan) ----------------
__global__ void k_scat(const int* __restrict__ src, const int* __restrict__ dst,
                       const int* __restrict__ pos, int* __restrict__ epad,
                       int2* __restrict__ ovf, int* __restrict__ ovfc) {
    int e = blockIdx.x * 256 + threadIdx.x;
    if (e < NE) {
        int d = dst[e], p = pos[e], s = src[e];
        if (p < SLOT) {
            epad[(size_t)d * SLOT + p] = s;
        } else {
            int o = atomicAdd(ovfc, 1);
            if (o < OVFCAP) ovf[o] = make_int2(d, s);
        }
    }
}

// ---------------- agg1: fp8 padded-slot gather-mean + bias + relu -> packed bf16 h1b ----------------
__global__ __launch_bounds__(256) void k_agg1(const unsigned char* __restrict__ t1f8,
                                              const int* __restrict__ cnt,
                                              const int* __restrict__ epad,
                                              const int2* __restrict__ ovf,
                                              const int* __restrict__ ovfc,
                                              const float* __restrict__ b1,
                                              unsigned* __restrict__ h1b) {
    const int tid = threadIdx.x;
    const int w = tid >> 6, l = tid & 63;
    const int n = blockIdx.x * 4 + w;
    if (n >= NN || l >= 50) return;
    const int deg = cnt[n];
    const int m = deg < SLOT ? deg : SLOT;
    const int* ep = epad + (size_t)n * SLOT;
    const int co = 2 * l;
    float acc0 = 0.f, acc1 = 0.f;
    int e = 0;
    for (; e + 7 < m; e += 8) {
        int s0 = ep[e],     s1 = ep[e + 1], s2 = ep[e + 2], s3 = ep[e + 3];
        int s4 = ep[e + 4], s5 = ep[e + 5], s6 = ep[e + 6], s7 = ep[e + 7];
        int u0 = *(const unsigned short*)(t1f8 + (size_t)s0 * PS1 + co);
        int u1 = *(const unsigned short*)(t1f8 + (size_t)s1 * PS1 + co);
        int u2 = *(const unsigned short*)(t1f8 + (size_t)s2 * PS1 + co);
        int u3 = *(const unsigned short*)(t1f8 + (size_t)s3 * PS1 + co);
        int u4 = *(const unsigned short*)(t1f8 + (size_t)s4 * PS1 + co);
        int u5 = *(const unsigned short*)(t1f8 + (size_t)s5 * PS1 + co);
        int u6 = *(const unsigned short*)(t1f8 + (size_t)s6 * PS1 + co);
        int u7 = *(const unsigned short*)(t1f8 + (size_t)s7 * PS1 + co);
        acc0 += __builtin_amdgcn_cvt_f32_fp8(u0, 0); acc1 += __builtin_amdgcn_cvt_f32_fp8(u0, 1);
        acc0 += __builtin_amdgcn_cvt_f32_fp8(u1, 0); acc1 += __builtin_amdgcn_cvt_f32_fp8(u1, 1);
        acc0 += __builtin_amdgcn_cvt_f32_fp8(u2, 0); acc1 += __builtin_amdgcn_cvt_f32_fp8(u2, 1);
        acc0 += __builtin_amdgcn_cvt_f32_fp8(u3, 0); acc1 += __builtin_amdgcn_cvt_f32_fp8(u3, 1);
        acc0 += __builtin_amdgcn_cvt_f32_fp8(u4, 0); acc1 += __builtin_amdgcn_cvt_f32_fp8(u4, 1);
        acc0 += __builtin_amdgcn_cvt_f32_fp8(u5, 0); acc1 += __builtin_amdgcn_cvt_f32_fp8(u5, 1);
        acc0 += __builtin_amdgcn_cvt_f32_fp8(u6, 0); acc1 += __builtin_amdgcn_cvt_f32_fp8(u6, 1);
        acc0 += __builtin_amdgcn_cvt_f32_fp8(u7, 0); acc1 += __builtin_amdgcn_cvt_f32_fp8(u7, 1);
    }
    for (; e < m; ++e) {
        int u = *(const unsigned short*)(t1f8 + (size_t)ep[e] * PS1 + co);
        acc0 += __builtin_amdgcn_cvt_f32_fp8(u, 0);
        acc1 += __builtin_amdgcn_cvt_f32_fp8(u, 1);
    }
    if (deg > SLOT) {
        int novf = *ovfc; novf = novf < OVFCAP ? novf : OVFCAP;
        for (int j2 = 0; j2 < novf; ++j2) {
            int2 p = ovf[j2];
            if (p.x == n) {
                int u = *(const unsigned short*)(t1f8 + (size_t)p.y * PS1 + co);
                acc0 += __builtin_amdgcn_cvt_f32_fp8(u, 0);
                acc1 += __builtin_amdgcn_cvt_f32_fp8(u, 1);
            }
        }
    }
    float d = (float)(deg > 0 ? deg : 1);
    float v0 = fmaxf(acc0 / d + b1[co], 0.f);
    float v1 = fmaxf(acc1 / d + b1[co + 1], 0.f);
    h1b[(size_t)n * 50 + l] = (unsigned)f2bf(v0) | ((unsigned)f2bf(v1) << 16);
}

// ---------------- GCN layer 2 GEMM: t2b (packed bf16) = h1 @ gc2_W ----------------
__global__ void k_gemm2(const unsigned* __restrict__ h1b, const float* __restrict__ W,
                        unsigned* __restrict__ t2b) {
    __shared__ float sW[C1 * C2];
    __shared__ float sr[16][C1];
    __shared__ float sc[16][C2];
    for (int idx = threadIdx.x; idx < C1 * C2; idx += 320) sW[idx] = W[idx];
    int ln = threadIdx.x / C2, j = threadIdx.x % C2;
    int n0 = blockIdx.x * 16;
    for (int idx = threadIdx.x; idx < 16 * 50; idx += 320) {
        int r = idx / 50, c = idx % 50;
        int n = n0 + r;
        unsigned u = (n < NN) ? h1b[(size_t)n * 50 + c] : 0u;
        sr[r][2 * c] = bf_lo(u);
        sr[r][2 * c + 1] = bf_hi(u);
    }
    __syncthreads();
    if (ln < 16) {
        float acc = 0.f;
        #pragma unroll 4
        for (int k = 0; k < C1; ++k) acc += sr[ln][k] * sW[k * C2 + j];
        sc[ln][j] = acc;
    }
    __syncthreads();
    for (int idx = threadIdx.x; idx < 16 * 10; idx += 320) {
        int r = idx / 10, jp = idx % 10;
        int n = n0 + r;
        if (n < NN)
            t2b[(size_t)n * 10 + jp] =
                (unsigned)f2bf(sc[r][2 * jp]) | ((unsigned)f2bf(sc[r][2 * jp + 1]) << 16);
    }
}

// ---------------- agg2 (padded-slot mean+bias+relu) + graph pool (atomic) ----------------
__global__ void k_agg2p(const unsigned* __restrict__ t2b, const int* __restrict__ cnt,
                        const int* __restrict__ epad, const int2* __restrict__ ovf,
                        const int* __restrict__ ovfc, const float* __restrict__ bias,
                        const int* __restrict__ gid, float* __restrict__ hgs) {
    int ln = threadIdx.x / C2, c = threadIdx.x % C2;
    if (ln >= 12) return;
    int n = blockIdx.x * 12 + ln;
    if (n >= NN) return;
    const int deg = cnt[n];
    const int m = deg < SLOT ? deg : SLOT;
    const int* ep = epad + (size_t)n * SLOT;
    const int jp = c >> 1, hi = c & 1;
    float acc = 0.f;
    int e = 0;
    for (; e + 3 < m; e += 4) {
        int s0 = ep[e], s1 = ep[e + 1], s2 = ep[e + 2], s3 = ep[e + 3];
        unsigned u0 = t2b[(size_t)s0 * 10 + jp];
        unsigned u1 = t2b[(size_t)s1 * 10 + jp];
        unsigned u2 = t2b[(size_t)s2 * 10 + jp];
        unsigned u3 = t2b[(size_t)s3 * 10 + jp];
        acc += hi ? bf_hi(u0) : bf_lo(u0);
        acc += hi ? bf_hi(u1) : bf_lo(u1);
        acc += hi ? bf_hi(u2) : bf_lo(u2);
        acc += hi ? bf_hi(u3) : bf_lo(u3);
    }
    for (; e < m; ++e) {
        unsigned u = t2b[(size_t)ep[e] * 10 + jp];
        acc += hi ? bf_hi(u) : bf_lo(u);
    }
    if (deg > SLOT) {
        int novf = *ovfc; novf = novf < OVFCAP ? novf : OVFCAP;
        for (int j2 = 0; j2 < novf; ++j2) {
            int2 p = ovf[j2];
            if (p.x == n) {
                unsigned u = t2b[(size_t)p.y * 10 + jp];
                acc += hi ? bf_hi(u) : bf_lo(u);
            }
        }
    }
    float d = (float)(deg > 0 ? deg : 1);
    float v = acc / d + bias[c];
    v = v > 0.f ? v : 0.f;
    atomicAdd(&hgs[gid[n] * C2 + c], v);
}

// ---------------- merged per-graph tail: hg div + attn head + fc1b (o1 write) ----------------
__global__ __launch_bounds__(128) void k_hfc1(const float* __restrict__ hgs,
                                              const int* __restrict__ gid,
                                              const float* __restrict__ desc2d,
                                              const float* __restrict__ pgW,
                                              const float* __restrict__ pgb,
                                              const float* __restrict__ p2W,
                                              const float* __restrict__ p2b,
                                              const float* __restrict__ W2,
                                              const float* __restrict__ V,
                                              const float* __restrict__ W1,
                                              float* __restrict__ o1) {
    __shared__ float shg[C2];
    __shared__ float sg[DHH];
    __shared__ float sa;
    const int b = blockIdx.x, tid = threadIdx.x;
    if (tid < C2) {
        int lo = 0, hi = NN;
        while (lo < hi) { int m = (lo + hi) >> 1; if (gid[m] < b) lo = m + 1; else hi = m; }
        int lo2 = lo, hi2 = NN;
        while (lo2 < hi2) { int m = (lo2 + hi2) >> 1; if (gid[m] < b + 1) lo2 = m + 1; else hi2 = m; }
        float dcnt = (float)(lo2 - lo);
        if (dcnt < 1.f) dcnt = 1.f;
        shg[tid] = hgs[b * C2 + tid] / dcnt;
    }
    __syncthreads();
    float hdj = 0.f;
    if (tid < DHH) {
        float hgj = pgb[tid];
        #pragma unroll
        for (int k = 0; k < C2; ++k) hgj += shg[k] * pgW[k * DHH + tid];
        hdj = p2b[tid];
        #pragma unroll 4
        for (int k = 0; k < DD2; ++k) hdj += desc2d[b * DD2 + k] * p2W[k * DHH + tid];
        sg[tid] = hgj;
    }
    __syncthreads();
    if (tid < DHH) {
        float tj = 0.f;
        #pragma unroll 4
        for (int k = 0; k < DHH; ++k) tj += sg[k] * W2[k * DHH + tid];
        float v = tj * hdj;
        #pragma unroll
        for (int off = 32; off; off >>= 1) v += __shfl_xor(v, off, 64);
        if (tid == 0) sa = 1.f / (1.f + expf(-v));
    }
    __syncthreads();
    const int j = tid;   // 0..127
    const float* Vb = V + (size_t)b * NU + j;
    const float* WL = W1 + (size_t)200 * HH1 + j;
    float sv = Vb[20 * HH1];
    float sw = WL[(size_t)20 * KD * HH1];
    #pragma unroll
    for (int i = 0; i < 20; ++i) {
        float h = shg[i];
        sv += h * Vb[i * HH1];
        sw += h * WL[(size_t)i * KD * HH1];
    }
    o1[b * HH1 + j] = sa * sv + sw;
}

// ---------------- fc2 (in-block bn1 stats) + last-block bn2/fc3 finale ----------------
__global__ __launch_bounds__(128) void k_fc2s(const float* __restrict__ o1,
                                              const float* __restrict__ g,
                                              const float* __restrict__ beta,
                                              const float* __restrict__ W,
                                              float* __restrict__ o2,
                                              const float* __restrict__ g2,
                                              const float* __restrict__ beta2,
                                              const float* __restrict__ W3,
                                              const float* __restrict__ b3,
                                              float* __restrict__ out,
                                              int* __restrict__ done) {
    __shared__ float r[HH1];
    __shared__ float part[4][HH2];
    __shared__ int amLast;
    const int tid = threadIdx.x;   // 128
    float s = 0.f, s2 = 0.f;
    for (int b = 0; b < NB; ++b) {
        float v = o1[b * HH1 + tid];
        s += v; s2 += v * v;
    }
    float mu = s / NB;
    float rstd = rsqrtf(s2 / NB - mu * mu + 1e-5f);
    float scale = rstd * g[tid];
    float shift = beta[tid] - mu * scale;
    const int m = tid & 31, p = tid >> 5;
    for (int q = 0; q < 4; ++q) {
        int b = blockIdx.x * 4 + q;
        float v = o1[b * HH1 + tid];
        __syncthreads();
        r[tid] = fmaxf(v * scale + shift, 0.f);
        __syncthreads();
        float acc = 0.f;
        #pragma unroll 4
        for (int j = p * 32; j < p * 32 + 32; ++j) acc += r[j] * W[j * HH2 + m];
        part[p][m] = acc;
        __syncthreads();
        if (tid < HH2) o2[b * HH2 + tid] = part[0][tid] + part[1][tid] + part[2][tid] + part[3][tid];
    }
    // ---- last block runs bn2 + relu + fc3 over all o2 ----
    __threadfence();
    if (tid == 0) amLast = (atomicAdd(done, 1) == (NB / 4) - 1);
    __syncthreads();
    if (!amLast) return;
    __shared__ float ps[4][HH2], ps2[4][HH2];
    __shared__ float sscale[HH2], sshift[HH2];
    {
        const int gq = tid >> 5, mm = tid & 31;
        float ts = 0.f, ts2 = 0.f;
        for (int rr = 0; rr < 128; ++rr) {
            float v = o2[(gq * 128 + rr) * HH2 + mm];
            ts += v; ts2 += v * v;
        }
        ps[gq][mm] = ts; ps2[gq][mm] = ts2;
    }
    __syncthreads();
    if (tid < HH2) {
        float ts = ps[0][tid] + ps[1][tid] + ps[2][tid] + ps[3][tid];
        float ts2 = ps2[0][tid] + ps2[1][tid] + ps2[2][tid] + ps2[3][tid];
        float mu2 = ts / NB;
        float rstd2 = rsqrtf(ts2 / NB - mu2 * mu2 + 1e-5f);
        float sc2 = rstd2 * g2[tid];
        sscale[tid] = sc2;
        sshift[tid] = beta2[tid] - mu2 * sc2;
    }
    __syncthreads();
    for (int b = tid; b < NB; b += 128) {
        float acc = b3[0];
        #pragma unroll 4
        for (int mm = 0; mm < HH2; ++mm) {
            float v = o2[b * HH2 + mm];
            acc += fmaxf(v * sscale[mm] + sshift[mm], 0.f) * W3[mm];
        }
        out[b] = acc;
    }
}

extern "C" void kernel_launch(void* const* d_in, const int* in_sizes, int n_in,
                              void* d_out, int out_size, void* d_ws, size_t ws_size,
                              hipStream_t stream) {
    const float* feat   = (const float*)d_in[0];
    const float* desc2d = (const float*)d_in[1];
    const float* gc1W = (const float*)d_in[3];
    const float* gc1b = (const float*)d_in[4];
    const float* gc2W = (const float*)d_in[5];
    const float* gc2b = (const float*)d_in[6];
    const float* pgW  = (const float*)d_in[7];
    const float* pgb  = (const float*)d_in[8];
    const float* p2W  = (const float*)d_in[9];
    const float* p2b  = (const float*)d_in[10];
    const float* W2   = (const float*)d_in[11];
    const float* fc1W = (const float*)d_in[12];
    const float* fc2W = (const float*)d_in[14];
    const float* fc3W = (const float*)d_in[16];
    const float* fc3b = (const float*)d_in[17];
    const float* bn1g = (const float*)d_in[18];
    const float* bn1b = (const float*)d_in[19];
    const float* bn2g = (const float*)d_in[20];
    const float* bn2b = (const float*)d_in[21];
    const int* src = (const int*)d_in[22];
    const int* dst = (const int*)d_in[23];
    const int* gid = (const int*)d_in[24];
    float* out = (float*)d_out;

    char* ws = (char*)d_ws;
    size_t off = 0;
    auto alloc = [&](size_t nb) {
        void* p = ws + off;
        off = (off + nb + 255) & ~(size_t)255;
        return p;
    };
    unsigned char* t1f8 = (unsigned char*)alloc((size_t)NN * PS1);   // 6.4 MB fp8
    unsigned* h1b = (unsigned*)alloc((size_t)NN * 50 * 4);           // 10 MB packed bf16
    unsigned* t2b = (unsigned*)alloc((size_t)NN * 10 * 4);           // 2 MB packed bf16
    int* cnt_in  = (int*)alloc((size_t)NN * 4);
    int* pos     = (int*)alloc((size_t)NE * 4);
    int* epad    = (int*)alloc((size_t)NN * SLOT * 4);               // 12.8 MB
    int2* ovf    = (int2*)alloc((size_t)OVFCAP * 8);
    int* ovfc    = (int*)alloc(256);
    int* done    = (int*)alloc(256);
    unsigned short* Bf = (unsigned short*)alloc((size_t)NCT * 4 * 64 * 16);  // 28 KB
    float* V     = (float*)alloc((size_t)NB * NU * 4);               // 5.5 MB
    float* hgs   = (float*)alloc((size_t)NB * C2 * 4);
    float* o1    = (float*)alloc((size_t)NB * HH1 * 4);
    float* o2    = (float*)alloc((size_t)NB * HH2 * 4);

    k_packB_init<<<SCB, 256, 0, stream>>>(gc1W, Bf, cnt_in, hgs, ovfc, done);
    k_front<<<FPB + GB1 + FCB, 256, 0, stream>>>(feat, Bf, t1f8, dst, cnt_in, pos,
                                                 desc2d, fc1W, V);
    k_scat<<<(NE + 255) / 256, 256, 0, stream>>>(src, dst, pos, epad, ovf, ovfc);

    k_agg1<<<(NN + 3) / 4, 256, 0, stream>>>(t1f8, cnt_in, epad, ovf, ovfc, gc1b, h1b);
    k_gemm2<<<(NN + 15) / 16, 320, 0, stream>>>(h1b, gc2W, t2b);
    k_agg2p<<<(NN + 11) / 12, 256, 0, stream>>>(t2b, cnt_in, epad, ovf, ovfc, gc2b, gid, hgs);

    k_hfc1<<<NB, 128, 0, stream>>>(hgs, gid, desc2d, pgW, pgb, p2W, p2b, W2, V, fc1W, o1);
    k_fc2s<<<NB / 4, 128, 0, stream>>>(o1, bn1g, bn1b, fc2W, o2,
                                       bn2g, bn2b, fc3W, fc3b, out, done);
}

// Round 19
// 183.882 us; speedup vs baseline: 4.0369x; 1.1091x over previous
//
#include <hip/hip_runtime.h>

#define NN 50000
#define NE 800000
#define NB 512
#define DIN 128
#define DD2 200
#define C1 100
#define C2 20
#define DHH 64
#define HH1 128
#define HH2 32
#define KD 201      // fusion inner dim per i (200 + 1)
#define KDP 204     // padded LDS row stride
#define NU 2688     // 21 * 128
#define SCB 196     // init blocks
#define NCT 7       // col tiles of 16 covering 100
#define NTILE 3125  // 50000 / 16 row tiles
#define GB1 782     // gemm1 blocks in k_front
#define FPB 3125    // fill blocks in k_front
#define FCB 672     // fc1V blocks in k_front
#define PS1 128     // t1 fp8 row stride (bytes)
#define SLOT 64     // padded edge slots per node
#define OVFCAP 8192
#define CSTR 16     // cnt stride (ints) -> one counter per 64B line

typedef short sh8 __attribute__((ext_vector_type(8)));
typedef float f32x4 __attribute__((ext_vector_type(4)));

__device__ __forceinline__ unsigned short f2bf(float x) {
    unsigned u = __float_as_uint(x);
    unsigned r = (u + 0x7fffu + ((u >> 16) & 1u)) >> 16;   // RNE
    return (unsigned short)r;
}
__device__ __forceinline__ float bf_lo(unsigned u) { return __uint_as_float(u << 16); }
__device__ __forceinline__ float bf_hi(unsigned u) { return __uint_as_float(u & 0xffff0000u); }

// ---------------- init: pack gc1_W into B-fragments + zero cnt(padded)/hgs/ovfc ----------------
__global__ void k_packB_init(const float* __restrict__ W, unsigned short* __restrict__ Bf,
                             int* __restrict__ cnt, float* __restrict__ hgs,
                             int* __restrict__ ovfc) {
    int idx = blockIdx.x * 256 + threadIdx.x;
    if (idx < NCT * 4 * 64) {
        int lane = idx & 63;
        int kc = (idx >> 6) & 3;
        int ct = idx >> 8;
        int col = ct * 16 + (lane & 15);
        int k0 = kc * 32 + (lane >> 4) * 8;
        unsigned short* outp = Bf + (size_t)idx * 8;
        #pragma unroll
        for (int e = 0; e < 8; ++e) {
            float v = (col < C1) ? W[(k0 + e) * C1 + col] : 0.f;
            outp[e] = f2bf(v);
        }
    }
    for (int i = idx; i < NN * CSTR; i += SCB * 256) cnt[i] = 0;
    if (idx < NB * C2) hgs[idx] = 0.f;
    if (idx == 0) *ovfc = 0;
}

// ---------------- fused front: gemm1 || fc1V || fillpos (compute segments first) ----------------
__global__ __launch_bounds__(256) void k_front(const float* __restrict__ feat,
                                               const unsigned short* __restrict__ Bf,
                                               unsigned char* __restrict__ t1f8,
                                               const int* __restrict__ dst,
                                               int* __restrict__ cnt,
                                               int* __restrict__ pos,
                                               const float* __restrict__ desc2d,
                                               const float* __restrict__ W1,
                                               float* __restrict__ V) {
    __shared__ float smem[7168];         // 28 KB, shared by gemm1 (sB) and fc1V (S)
    const int tid = threadIdx.x;

    if (blockIdx.x >= GB1 + FCB) {
        // ---- fillpos: one atomic pass on line-padded counters, coalesced pos write ----
        int e = (blockIdx.x - GB1 - FCB) * 256 + tid;
        if (e < NE) pos[e] = atomicAdd(&cnt[dst[e] * CSTR], 1);
        return;
    }

    if (blockIdx.x < GB1) {
        // ---- gemm1 via MFMA ----
        sh8* sB = (sh8*)smem;            // [NCT][4][64]
        {
            const uint4* srcp = (const uint4*)Bf;
            uint4* dstp = (uint4*)smem;
            for (int i = tid; i < NCT * 4 * 64; i += 256) dstp[i] = srcp[i];
        }
        __syncthreads();
        const int w = tid >> 6, lane = tid & 63;
        const int ri = lane & 15;
        const int kg = lane >> 4;
        int tile = blockIdx.x * 4 + w;
        if (tile < NTILE) {
            const int n = tile * 16 + ri;
            f32x4 acc[NCT];
            #pragma unroll
            for (int ct = 0; ct < NCT; ++ct) acc[ct] = (f32x4){0.f, 0.f, 0.f, 0.f};
            #pragma unroll
            for (int kc = 0; kc < 4; ++kc) {
                const float* ap = feat + (size_t)n * DIN + kc * 32 + kg * 8;
                float4 a0 = *(const float4*)ap;
                float4 a1 = *(const float4*)(ap + 4);
                union { sh8 v; unsigned short u[8]; } af;
                af.u[0] = f2bf(a0.x); af.u[1] = f2bf(a0.y);
                af.u[2] = f2bf(a0.z); af.u[3] = f2bf(a0.w);
                af.u[4] = f2bf(a1.x); af.u[5] = f2bf(a1.y);
                af.u[6] = f2bf(a1.z); af.u[7] = f2bf(a1.w);
                #pragma unroll
                for (int ct = 0; ct < NCT; ++ct)
                    acc[ct] = __builtin_amdgcn_mfma_f32_16x16x32_bf16(
                        af.v, sB[(ct * 4 + kc) * 64 + lane], acc[ct], 0, 0, 0);
            }
            const int rbase = tile * 16 + kg * 4;
            #pragma unroll
            for (int ct = 0; ct < NCT; ++ct) {
                int col = ct * 16 + ri;
                if (col < C1) {
                    #pragma unroll
                    for (int r = 0; r < 4; ++r) {
                        int pk = __builtin_amdgcn_cvt_pk_fp8_f32(acc[ct][r], acc[ct][r], 0, false);
                        t1f8[(size_t)(rbase + r) * PS1 + col] = (unsigned char)(pk & 0xFF);
                    }
                }
            }
        }
        return;
    }

    // ---- fc1V: V[b][i*128+j] = sum_{k<200} desc2d[b][k] * W1[(i*201+k)*128+j] ----
    {
        float (*S)[KDP] = (float(*)[KDP])smem;   // [32][204]
        int fid = blockIdx.x - GB1;              // 0..671
        const int i = fid / 32;
        const int rem = fid % 32;
        const int bt = rem >> 1;
        const int half = rem & 1;
        for (int idx = tid; idx < 32 * 50; idx += 256) {
            int r = idx / 50, c4 = idx % 50;
            *(float4*)&S[r][c4 * 4] =
                *(const float4*)(desc2d + (size_t)(bt * 32 + r) * DD2 + c4 * 4);
        }
        __syncthreads();
        const int c = tid & 31;
        const int rg = tid >> 5;
        float acc[4][2];
        #pragma unroll
        for (int r = 0; r < 4; ++r) { acc[r][0] = 0.f; acc[r][1] = 0.f; }
        const float* Wb = W1 + (size_t)i * (KD * HH1) + half * 64 + c;
        for (int k = 0; k < 200; k += 4) {
            const float* Wk = Wb + (size_t)k * HH1;
            float w0[2], w1[2], w2[2], w3[2];
            #pragma unroll
            for (int m = 0; m < 2; ++m) {
                w0[m] = Wk[32 * m];
                w1[m] = Wk[HH1 + 32 * m];
                w2[m] = Wk[2 * HH1 + 32 * m];
                w3[m] = Wk[3 * HH1 + 32 * m];
            }
            #pragma unroll
            for (int r = 0; r < 4; ++r) {
                float4 a4 = *(const float4*)&S[rg * 4 + r][k];
                #pragma unroll
                for (int m = 0; m < 2; ++m)
                    acc[r][m] += a4.x * w0[m] + a4.y * w1[m] + a4.z * w2[m] + a4.w * w3[m];
            }
        }
        #pragma unroll
        for (int r = 0; r < 4; ++r) {
            int b = bt * 32 + rg * 4 + r;
            float* Vr = V + (size_t)b * NU + i * HH1 + half * 64 + c;
            Vr[0] = acc[r][0];
            Vr[32] = acc[r][1];
        }
    }
}

// ---------------- scatter src into padded slots (no atomics, no scan) ----------------
__global__ void k_scat(const int* __restrict__ src, const int* __restrict__ dst,
                       const int* __restrict__ pos, int* __restrict__ epad,
                       int2* __restrict__ ovf, int* __restrict__ ovfc) {
    int e = blockIdx.x * 256 + threadIdx.x;
    if (e < NE) {
        int d = dst[e], p = pos[e], s = src[e];
        if (p < SLOT) {
            epad[(size_t)d * SLOT + p] = s;
        } else {
            int o = atomicAdd(ovfc, 1);
            if (o < OVFCAP) ovf[o] = make_int2(d, s);
        }
    }
}

// ---------------- agg1: fp8 padded-slot gather-mean + bias + relu -> packed bf16 h1b ----------------
__global__ __launch_bounds__(256) void k_agg1(const unsigned char* __restrict__ t1f8,
                                              const int* __restrict__ cnt,
                                              const int* __restrict__ epad,
                                              const int2* __restrict__ ovf,
                                              const int* __restrict__ ovfc,
                                              const float* __restrict__ b1,
                                              unsigned* __restrict__ h1b) {
    const int tid = threadIdx.x;
    const int w = tid >> 6, l = tid & 63;
    const int n = blockIdx.x * 4 + w;
    if (n >= NN || l >= 50) return;
    const int deg = cnt[n * CSTR];
    const int m = deg < SLOT ? deg : SLOT;
    const int* ep = epad + (size_t)n * SLOT;
    const int co = 2 * l;
    float acc0 = 0.f, acc1 = 0.f;
    int e = 0;
    for (; e + 7 < m; e += 8) {
        int s0 = ep[e],     s1 = ep[e + 1], s2 = ep[e + 2], s3 = ep[e + 3];
        int s4 = ep[e + 4], s5 = ep[e + 5], s6 = ep[e + 6], s7 = ep[e + 7];
        int u0 = *(const unsigned short*)(t1f8 + (size_t)s0 * PS1 + co);
        int u1 = *(const unsigned short*)(t1f8 + (size_t)s1 * PS1 + co);
        int u2 = *(const unsigned short*)(t1f8 + (size_t)s2 * PS1 + co);
        int u3 = *(const unsigned short*)(t1f8 + (size_t)s3 * PS1 + co);
        int u4 = *(const unsigned short*)(t1f8 + (size_t)s4 * PS1 + co);
        int u5 = *(const unsigned short*)(t1f8 + (size_t)s5 * PS1 + co);
        int u6 = *(const unsigned short*)(t1f8 + (size_t)s6 * PS1 + co);
        int u7 = *(const unsigned short*)(t1f8 + (size_t)s7 * PS1 + co);
        acc0 += __builtin_amdgcn_cvt_f32_fp8(u0, 0); acc1 += __builtin_amdgcn_cvt_f32_fp8(u0, 1);
        acc0 += __builtin_amdgcn_cvt_f32_fp8(u1, 0); acc1 += __builtin_amdgcn_cvt_f32_fp8(u1, 1);
        acc0 += __builtin_amdgcn_cvt_f32_fp8(u2, 0); acc1 += __builtin_amdgcn_cvt_f32_fp8(u2, 1);
        acc0 += __builtin_amdgcn_cvt_f32_fp8(u3, 0); acc1 += __builtin_amdgcn_cvt_f32_fp8(u3, 1);
        acc0 += __builtin_amdgcn_cvt_f32_fp8(u4, 0); acc1 += __builtin_amdgcn_cvt_f32_fp8(u4, 1);
        acc0 += __builtin_amdgcn_cvt_f32_fp8(u5, 0); acc1 += __builtin_amdgcn_cvt_f32_fp8(u5, 1);
        acc0 += __builtin_amdgcn_cvt_f32_fp8(u6, 0); acc1 += __builtin_amdgcn_cvt_f32_fp8(u6, 1);
        acc0 += __builtin_amdgcn_cvt_f32_fp8(u7, 0); acc1 += __builtin_amdgcn_cvt_f32_fp8(u7, 1);
    }
    for (; e < m; ++e) {
        int u = *(const unsigned short*)(t1f8 + (size_t)ep[e] * PS1 + co);
        acc0 += __builtin_amdgcn_cvt_f32_fp8(u, 0);
        acc1 += __builtin_amdgcn_cvt_f32_fp8(u, 1);
    }
    if (deg > SLOT) {
        int novf = *ovfc; novf = novf < OVFCAP ? novf : OVFCAP;
        for (int j2 = 0; j2 < novf; ++j2) {
            int2 p = ovf[j2];
            if (p.x == n) {
                int u = *(const unsigned short*)(t1f8 + (size_t)p.y * PS1 + co);
                acc0 += __builtin_amdgcn_cvt_f32_fp8(u, 0);
                acc1 += __builtin_amdgcn_cvt_f32_fp8(u, 1);
            }
        }
    }
    float d = (float)(deg > 0 ? deg : 1);
    float v0 = fmaxf(acc0 / d + b1[co], 0.f);
    float v1 = fmaxf(acc1 / d + b1[co + 1], 0.f);
    h1b[(size_t)n * 50 + l] = (unsigned)f2bf(v0) | ((unsigned)f2bf(v1) << 16);
}

// ---------------- GCN layer 2 GEMM: t2b (packed bf16) = h1 @ gc2_W ----------------
__global__ void k_gemm2(const unsigned* __restrict__ h1b, const float* __restrict__ W,
                        unsigned* __restrict__ t2b) {
    __shared__ float sW[C1 * C2];
    __shared__ float sr[16][C1];
    __shared__ float sc[16][C2];
    for (int idx = threadIdx.x; idx < C1 * C2; idx += 320) sW[idx] = W[idx];
    int ln = threadIdx.x / C2, j = threadIdx.x % C2;
    int n0 = blockIdx.x * 16;
    for (int idx = threadIdx.x; idx < 16 * 50; idx += 320) {
        int r = idx / 50, c = idx % 50;
        int n = n0 + r;
        unsigned u = (n < NN) ? h1b[(size_t)n * 50 + c] : 0u;
        sr[r][2 * c] = bf_lo(u);
        sr[r][2 * c + 1] = bf_hi(u);
    }
    __syncthreads();
    if (ln < 16) {
        float acc = 0.f;
        #pragma unroll 4
        for (int k = 0; k < C1; ++k) acc += sr[ln][k] * sW[k * C2 + j];
        sc[ln][j] = acc;
    }
    __syncthreads();
    for (int idx = threadIdx.x; idx < 16 * 10; idx += 320) {
        int r = idx / 10, jp = idx % 10;
        int n = n0 + r;
        if (n < NN)
            t2b[(size_t)n * 10 + jp] =
                (unsigned)f2bf(sc[r][2 * jp]) | ((unsigned)f2bf(sc[r][2 * jp + 1]) << 16);
    }
}

// ---------------- agg2 (padded-slot mean+bias+relu) + graph pool (atomic) ----------------
__global__ void k_agg2p(const unsigned* __restrict__ t2b, const int* __restrict__ cnt,
                        const int* __restrict__ epad, const int2* __restrict__ ovf,
                        const int* __restrict__ ovfc, const float* __restrict__ bias,
                        const int* __restrict__ gid, float* __restrict__ hgs) {
    int ln = threadIdx.x / C2, c = threadIdx.x % C2;
    if (ln >= 12) return;
    int n = blockIdx.x * 12 + ln;
    if (n >= NN) return;
    const int deg = cnt[n * CSTR];
    const int m = deg < SLOT ? deg : SLOT;
    const int* ep = epad + (size_t)n * SLOT;
    const int jp = c >> 1, hi = c & 1;
    float acc = 0.f;
    int e = 0;
    for (; e + 3 < m; e += 4) {
        int s0 = ep[e], s1 = ep[e + 1], s2 = ep[e + 2], s3 = ep[e + 3];
        unsigned u0 = t2b[(size_t)s0 * 10 + jp];
        unsigned u1 = t2b[(size_t)s1 * 10 + jp];
        unsigned u2 = t2b[(size_t)s2 * 10 + jp];
        unsigned u3 = t2b[(size_t)s3 * 10 + jp];
        acc += hi ? bf_hi(u0) : bf_lo(u0);
        acc += hi ? bf_hi(u1) : bf_lo(u1);
        acc += hi ? bf_hi(u2) : bf_lo(u2);
        acc += hi ? bf_hi(u3) : bf_lo(u3);
    }
    for (; e < m; ++e) {
        unsigned u = t2b[(size_t)ep[e] * 10 + jp];
        acc += hi ? bf_hi(u) : bf_lo(u);
    }
    if (deg > SLOT) {
        int novf = *ovfc; novf = novf < OVFCAP ? novf : OVFCAP;
        for (int j2 = 0; j2 < novf; ++j2) {
            int2 p = ovf[j2];
            if (p.x == n) {
                unsigned u = t2b[(size_t)p.y * 10 + jp];
                acc += hi ? bf_hi(u) : bf_lo(u);
            }
        }
    }
    float d = (float)(deg > 0 ? deg : 1);
    float v = acc / d + bias[c];
    v = v > 0.f ? v : 0.f;
    atomicAdd(&hgs[gid[n] * C2 + c], v);
}

// ---------------- merged per-graph tail: hg div + attn head + fc1b (o1 write) ----------------
__global__ __launch_bounds__(128) void k_hfc1(const float* __restrict__ hgs,
                                              const int* __restrict__ gid,
                                              const float* __restrict__ desc2d,
                                              const float* __restrict__ pgW,
                                              const float* __restrict__ pgb,
                                              const float* __restrict__ p2W,
                                              const float* __restrict__ p2b,
                                              const float* __restrict__ W2,
                                              const float* __restrict__ V,
                                              const float* __restrict__ W1,
                                              float* __restrict__ o1) {
    __shared__ float shg[C2];
    __shared__ float sg[DHH];
    __shared__ float sa;
    const int b = blockIdx.x, tid = threadIdx.x;
    if (tid < C2) {
        int lo = 0, hi = NN;
        while (lo < hi) { int m = (lo + hi) >> 1; if (gid[m] < b) lo = m + 1; else hi = m; }
        int lo2 = lo, hi2 = NN;
        while (lo2 < hi2) { int m = (lo2 + hi2) >> 1; if (gid[m] < b + 1) lo2 = m + 1; else hi2 = m; }
        float dcnt = (float)(lo2 - lo);
        if (dcnt < 1.f) dcnt = 1.f;
        shg[tid] = hgs[b * C2 + tid] / dcnt;
    }
    __syncthreads();
    float hdj = 0.f;
    if (tid < DHH) {
        float hgj = pgb[tid];
        #pragma unroll
        for (int k = 0; k < C2; ++k) hgj += shg[k] * pgW[k * DHH + tid];
        hdj = p2b[tid];
        #pragma unroll 4
        for (int k = 0; k < DD2; ++k) hdj += desc2d[b * DD2 + k] * p2W[k * DHH + tid];
        sg[tid] = hgj;
    }
    __syncthreads();
    if (tid < DHH) {
        float tj = 0.f;
        #pragma unroll 4
        for (int k = 0; k < DHH; ++k) tj += sg[k] * W2[k * DHH + tid];
        float v = tj * hdj;
        #pragma unroll
        for (int off = 32; off; off >>= 1) v += __shfl_xor(v, off, 64);
        if (tid == 0) sa = 1.f / (1.f + expf(-v));
    }
    __syncthreads();
    const int j = tid;   // 0..127
    const float* Vb = V + (size_t)b * NU + j;
    const float* WL = W1 + (size_t)200 * HH1 + j;
    float sv = Vb[20 * HH1];
    float sw = WL[(size_t)20 * KD * HH1];
    #pragma unroll
    for (int i = 0; i < 20; ++i) {
        float h = shg[i];
        sv += h * Vb[i * HH1];
        sw += h * WL[(size_t)i * KD * HH1];
    }
    o1[b * HH1 + j] = sa * sv + sw;
}

// ---------------- fc2 with in-block bn1 stats ----------------
__global__ __launch_bounds__(128) void k_fc2s(const float* __restrict__ o1,
                                              const float* __restrict__ g,
                                              const float* __restrict__ beta,
                                              const float* __restrict__ W,
                                              float* __restrict__ o2) {
    __shared__ float r[HH1];
    __shared__ float part[4][HH2];
    const int tid = threadIdx.x;   // 128
    float s = 0.f, s2 = 0.f;
    for (int b = 0; b < NB; ++b) {
        float v = o1[b * HH1 + tid];
        s += v; s2 += v * v;
    }
    float mu = s / NB;
    float rstd = rsqrtf(s2 / NB - mu * mu + 1e-5f);
    float scale = rstd * g[tid];
    float shift = beta[tid] - mu * scale;
    const int m = tid & 31, p = tid >> 5;
    for (int q = 0; q < 4; ++q) {
        int b = blockIdx.x * 4 + q;
        float v = o1[b * HH1 + tid];
        __syncthreads();
        r[tid] = fmaxf(v * scale + shift, 0.f);
        __syncthreads();
        float acc = 0.f;
        #pragma unroll 4
        for (int j = p * 32; j < p * 32 + 32; ++j) acc += r[j] * W[j * HH2 + m];
        part[p][m] = acc;
        __syncthreads();
        if (tid < HH2) o2[b * HH2 + tid] = part[0][tid] + part[1][tid] + part[2][tid] + part[3][tid];
    }
}

// ---------------- final: in-block bn2 stats + relu + fc3 ----------------
__global__ __launch_bounds__(512) void k_finals(const float* __restrict__ o2,
                                                const float* __restrict__ g,
                                                const float* __restrict__ beta,
                                                const float* __restrict__ W3,
                                                const float* __restrict__ b3,
                                                float* __restrict__ out) {
    __shared__ float ps[16][HH2], ps2[16][HH2];
    __shared__ float sscale[HH2], sshift[HH2];
    const int tid = threadIdx.x;    // 512
    const int gq = tid >> 5, m = tid & 31;
    float s = 0.f, s2 = 0.f;
    for (int rr = 0; rr < 32; ++rr) {
        float v = o2[(gq * 32 + rr) * HH2 + m];
        s += v; s2 += v * v;
    }
    ps[gq][m] = s; ps2[gq][m] = s2;
    __syncthreads();
    if (tid < HH2) {
        float ts = 0.f, ts2 = 0.f;
        #pragma unroll
        for (int q = 0; q < 16; ++q) { ts += ps[q][tid]; ts2 += ps2[q][tid]; }
        float mu = ts / NB;
        float rstd = rsqrtf(ts2 / NB - mu * mu + 1e-5f);
        float scale = rstd * g[tid];
        sscale[tid] = scale;
        sshift[tid] = beta[tid] - mu * scale;
    }
    __syncthreads();
    float acc = b3[0];
    #pragma unroll 4
    for (int mm = 0; mm < HH2; ++mm) {
        float v = o2[tid * HH2 + mm];
        acc += fmaxf(v * sscale[mm] + sshift[mm], 0.f) * W3[mm];
    }
    out[tid] = acc;
}

extern "C" void kernel_launch(void* const* d_in, const int* in_sizes, int n_in,
                              void* d_out, int out_size, void* d_ws, size_t ws_size,
                              hipStream_t stream) {
    const float* feat   = (const float*)d_in[0];
    const float* desc2d = (const float*)d_in[1];
    const float* gc1W = (const float*)d_in[3];
    const float* gc1b = (const float*)d_in[4];
    const float* gc2W = (const float*)d_in[5];
    const float* gc2b = (const float*)d_in[6];
    const float* pgW  = (const float*)d_in[7];
    const float* pgb  = (const float*)d_in[8];
    const float* p2W  = (const float*)d_in[9];
    const float* p2b  = (const float*)d_in[10];
    const float* W2   = (const float*)d_in[11];
    const float* fc1W = (const float*)d_in[12];
    const float* fc2W = (const float*)d_in[14];
    const float* fc3W = (const float*)d_in[16];
    const float* fc3b = (const float*)d_in[17];
    const float* bn1g = (const float*)d_in[18];
    const float* bn1b = (const float*)d_in[19];
    const float* bn2g = (const float*)d_in[20];
    const float* bn2b = (const float*)d_in[21];
    const int* src = (const int*)d_in[22];
    const int* dst = (const int*)d_in[23];
    const int* gid = (const int*)d_in[24];
    float* out = (float*)d_out;

    char* ws = (char*)d_ws;
    size_t off = 0;
    auto alloc = [&](size_t nb) {
        void* p = ws + off;
        off = (off + nb + 255) & ~(size_t)255;
        return p;
    };
    unsigned char* t1f8 = (unsigned char*)alloc((size_t)NN * PS1);   // 6.4 MB fp8
    unsigned* h1b = (unsigned*)alloc((size_t)NN * 50 * 4);           // 10 MB packed bf16
    unsigned* t2b = (unsigned*)alloc((size_t)NN * 10 * 4);           // 2 MB packed bf16
    int* cnt_in  = (int*)alloc((size_t)NN * CSTR * 4);               // 3.2 MB line-padded
    int* pos     = (int*)alloc((size_t)NE * 4);
    int* epad    = (int*)alloc((size_t)NN * SLOT * 4);               // 12.8 MB
    int2* ovf    = (int2*)alloc((size_t)OVFCAP * 8);
    int* ovfc    = (int*)alloc(256);
    unsigned short* Bf = (unsigned short*)alloc((size_t)NCT * 4 * 64 * 16);  // 28 KB
    float* V     = (float*)alloc((size_t)NB * NU * 4);               // 5.5 MB
    float* hgs   = (float*)alloc((size_t)NB * C2 * 4);
    float* o1    = (float*)alloc((size_t)NB * HH1 * 4);
    float* o2    = (float*)alloc((size_t)NB * HH2 * 4);

    k_packB_init<<<SCB, 256, 0, stream>>>(gc1W, Bf, cnt_in, hgs, ovfc);
    k_front<<<GB1 + FCB + FPB, 256, 0, stream>>>(feat, Bf, t1f8, dst, cnt_in, pos,
                                                 desc2d, fc1W, V);
    k_scat<<<(NE + 255) / 256, 256, 0, stream>>>(src, dst, pos, epad, ovf, ovfc);

    k_agg1<<<(NN + 3) / 4, 256, 0, stream>>>(t1f8, cnt_in, epad, ovf, ovfc, gc1b, h1b);
    k_gemm2<<<(NN + 15) / 16, 320, 0, stream>>>(h1b, gc2W, t2b);
    k_agg2p<<<(NN + 11) / 12, 256, 0, stream>>>(t2b, cnt_in, epad, ovf, ovfc, gc2b, gid, hgs);

    k_hfc1<<<NB, 128, 0, stream>>>(hgs, gid, desc2d, pgW, pgb, p2W, p2b, W2, V, fc1W, o1);
    k_fc2s<<<NB / 4, 128, 0, stream>>>(o1, bn1g, bn1b, fc2W, o2);
    k_finals<<<1, 512, 0, stream>>>(o2, bn2g, bn2b, fc3W, fc3b, out);
}

// Round 20
// 183.134 us; speedup vs baseline: 4.0534x; 1.0041x over previous
//
#include <hip/hip_runtime.h>

#define NN 50000
#define NE 800000
#define NB 512
#define DIN 128
#define DD2 200
#define C1 100
#define C2 20
#define DHH 64
#define HH1 128
#define HH2 32
#define KD 201      // fusion inner dim per i (200 + 1)
#define KDP 204     // padded LDS row stride
#define NU 2688     // 21 * 128
#define SCB 196     // init blocks
#define NCT 7       // col tiles of 16 covering 100
#define NTILE 3125  // 50000 / 16 row tiles
#define GB1 782     // gemm1 blocks in k_front
#define FPB 3125    // fill blocks in k_front
#define FCB 672     // fc1V blocks in k_front
#define PS1 128     // t1 fp8 row stride (bytes)
#define SLOT 32     // padded edge slots per node (u16) -> 64B/node index row
#define OVFCAP 8192
#define CSTR 16     // cnt stride (ints) -> one counter per 64B line

typedef short sh8 __attribute__((ext_vector_type(8)));
typedef float f32x4 __attribute__((ext_vector_type(4)));

__device__ __forceinline__ unsigned short f2bf(float x) {
    unsigned u = __float_as_uint(x);
    unsigned r = (u + 0x7fffu + ((u >> 16) & 1u)) >> 16;   // RNE
    return (unsigned short)r;
}
__device__ __forceinline__ float bf_lo(unsigned u) { return __uint_as_float(u << 16); }
__device__ __forceinline__ float bf_hi(unsigned u) { return __uint_as_float(u & 0xffff0000u); }

// ---------------- init: pack gc1_W into B-fragments + zero cnt(padded)/hgs/ovfc ----------------
__global__ void k_packB_init(const float* __restrict__ W, unsigned short* __restrict__ Bf,
                             int* __restrict__ cnt, float* __restrict__ hgs,
                             int* __restrict__ ovfc) {
    int idx = blockIdx.x * 256 + threadIdx.x;
    if (idx < NCT * 4 * 64) {
        int lane = idx & 63;
        int kc = (idx >> 6) & 3;
        int ct = idx >> 8;
        int col = ct * 16 + (lane & 15);
        int k0 = kc * 32 + (lane >> 4) * 8;
        unsigned short* outp = Bf + (size_t)idx * 8;
        #pragma unroll
        for (int e = 0; e < 8; ++e) {
            float v = (col < C1) ? W[(k0 + e) * C1 + col] : 0.f;
            outp[e] = f2bf(v);
        }
    }
    for (int i = idx; i < NN * CSTR; i += SCB * 256) cnt[i] = 0;
    if (idx < NB * C2) hgs[idx] = 0.f;
    if (idx == 0) *ovfc = 0;
}

// ---------------- fused front: gemm1 || fc1V || fillpos (compute segments first) ----------------
__global__ __launch_bounds__(256) void k_front(const float* __restrict__ feat,
                                               const unsigned short* __restrict__ Bf,
                                               unsigned char* __restrict__ t1f8,
                                               const int* __restrict__ dst,
                                               int* __restrict__ cnt,
                                               int* __restrict__ pos,
                                               const float* __restrict__ desc2d,
                                               const float* __restrict__ W1,
                                               float* __restrict__ V) {
    __shared__ float smem[7168];         // 28 KB, shared by gemm1 (sB) and fc1V (S)
    const int tid = threadIdx.x;

    if (blockIdx.x >= GB1 + FCB) {
        // ---- fillpos: one atomic pass on line-padded counters, coalesced pos write ----
        int e = (blockIdx.x - GB1 - FCB) * 256 + tid;
        if (e < NE) pos[e] = atomicAdd(&cnt[dst[e] * CSTR], 1);
        return;
    }

    if (blockIdx.x < GB1) {
        // ---- gemm1 via MFMA ----
        sh8* sB = (sh8*)smem;            // [NCT][4][64]
        {
            const uint4* srcp = (const uint4*)Bf;
            uint4* dstp = (uint4*)smem;
            for (int i = tid; i < NCT * 4 * 64; i += 256) dstp[i] = srcp[i];
        }
        __syncthreads();
        const int w = tid >> 6, lane = tid & 63;
        const int ri = lane & 15;
        const int kg = lane >> 4;
        int tile = blockIdx.x * 4 + w;
        if (tile < NTILE) {
            const int n = tile * 16 + ri;
            f32x4 acc[NCT];
            #pragma unroll
            for (int ct = 0; ct < NCT; ++ct) acc[ct] = (f32x4){0.f, 0.f, 0.f, 0.f};
            #pragma unroll
            for (int kc = 0; kc < 4; ++kc) {
                const float* ap = feat + (size_t)n * DIN + kc * 32 + kg * 8;
                float4 a0 = *(const float4*)ap;
                float4 a1 = *(const float4*)(ap + 4);
                union { sh8 v; unsigned short u[8]; } af;
                af.u[0] = f2bf(a0.x); af.u[1] = f2bf(a0.y);
                af.u[2] = f2bf(a0.z); af.u[3] = f2bf(a0.w);
                af.u[4] = f2bf(a1.x); af.u[5] = f2bf(a1.y);
                af.u[6] = f2bf(a1.z); af.u[7] = f2bf(a1.w);
                #pragma unroll
                for (int ct = 0; ct < NCT; ++ct)
                    acc[ct] = __builtin_amdgcn_mfma_f32_16x16x32_bf16(
                        af.v, sB[(ct * 4 + kc) * 64 + lane], acc[ct], 0, 0, 0);
            }
            const int rbase = tile * 16 + kg * 4;
            #pragma unroll
            for (int ct = 0; ct < NCT; ++ct) {
                int col = ct * 16 + ri;
                if (col < C1) {
                    #pragma unroll
                    for (int r = 0; r < 4; ++r) {
                        int pk = __builtin_amdgcn_cvt_pk_fp8_f32(acc[ct][r], acc[ct][r], 0, false);
                        t1f8[(size_t)(rbase + r) * PS1 + col] = (unsigned char)(pk & 0xFF);
                    }
                }
            }
        }
        return;
    }

    // ---- fc1V: V[b][i*128+j] = sum_{k<200} desc2d[b][k] * W1[(i*201+k)*128+j] ----
    {
        float (*S)[KDP] = (float(*)[KDP])smem;   // [32][204]
        int fid = blockIdx.x - GB1;              // 0..671
        const int i = fid / 32;
        const int rem = fid % 32;
        const int bt = rem >> 1;
        const int half = rem & 1;
        for (int idx = tid; idx < 32 * 50; idx += 256) {
            int r = idx / 50, c4 = idx % 50;
            *(float4*)&S[r][c4 * 4] =
                *(const float4*)(desc2d + (size_t)(bt * 32 + r) * DD2 + c4 * 4);
        }
        __syncthreads();
        const int c = tid & 31;
        const int rg = tid >> 5;
        float acc[4][2];
        #pragma unroll
        for (int r = 0; r < 4; ++r) { acc[r][0] = 0.f; acc[r][1] = 0.f; }
        const float* Wb = W1 + (size_t)i * (KD * HH1) + half * 64 + c;
        for (int k = 0; k < 200; k += 4) {
            const float* Wk = Wb + (size_t)k * HH1;
            float w0[2], w1[2], w2[2], w3[2];
            #pragma unroll
            for (int m = 0; m < 2; ++m) {
                w0[m] = Wk[32 * m];
                w1[m] = Wk[HH1 + 32 * m];
                w2[m] = Wk[2 * HH1 + 32 * m];
                w3[m] = Wk[3 * HH1 + 32 * m];
            }
            #pragma unroll
            for (int r = 0; r < 4; ++r) {
                float4 a4 = *(const float4*)&S[rg * 4 + r][k];
                #pragma unroll
                for (int m = 0; m < 2; ++m)
                    acc[r][m] += a4.x * w0[m] + a4.y * w1[m] + a4.z * w2[m] + a4.w * w3[m];
            }
        }
        #pragma unroll
        for (int r = 0; r < 4; ++r) {
            int b = bt * 32 + rg * 4 + r;
            float* Vr = V + (size_t)b * NU + i * HH1 + half * 64 + c;
            Vr[0] = acc[r][0];
            Vr[32] = acc[r][1];
        }
    }
}

// ---------------- scatter src into padded u16 slots (no atomics, no scan) ----------------
__global__ void k_scat(const int* __restrict__ src, const int* __restrict__ dst,
                       const int* __restrict__ pos, unsigned short* __restrict__ epad,
                       int2* __restrict__ ovf, int* __restrict__ ovfc) {
    int e = blockIdx.x * 256 + threadIdx.x;
    if (e < NE) {
        int d = dst[e], p = pos[e], s = src[e];
        if (p < SLOT) {
            epad[(size_t)d * SLOT + p] = (unsigned short)s;
        } else {
            int o = atomicAdd(ovfc, 1);
            if (o < OVFCAP) ovf[o] = make_int2(d, s);
        }
    }
}

// ---------------- agg1: fp8 padded-slot gather-mean + bias + relu -> packed bf16 h1b ----------------
__global__ __launch_bounds__(256) void k_agg1(const unsigned char* __restrict__ t1f8,
                                              const int* __restrict__ cnt,
                                              const unsigned short* __restrict__ epad,
                                              const int2* __restrict__ ovf,
                                              const int* __restrict__ ovfc,
                                              const float* __restrict__ b1,
                                              unsigned* __restrict__ h1b) {
    const int tid = threadIdx.x;
    const int w = tid >> 6, l = tid & 63;
    const int n = blockIdx.x * 4 + w;
    if (n >= NN || l >= 50) return;
    const int deg = cnt[n * CSTR];
    const int m = deg < SLOT ? deg : SLOT;
    const unsigned short* ep = epad + (size_t)n * SLOT;
    const int co = 2 * l;
    float acc0 = 0.f, acc1 = 0.f;
    int e = 0;
    for (; e + 7 < m; e += 8) {
        int s0 = ep[e],     s1 = ep[e + 1], s2 = ep[e + 2], s3 = ep[e + 3];
        int s4 = ep[e + 4], s5 = ep[e + 5], s6 = ep[e + 6], s7 = ep[e + 7];
        int u0 = *(const unsigned short*)(t1f8 + (size_t)s0 * PS1 + co);
        int u1 = *(const unsigned short*)(t1f8 + (size_t)s1 * PS1 + co);
        int u2 = *(const unsigned short*)(t1f8 + (size_t)s2 * PS1 + co);
        int u3 = *(const unsigned short*)(t1f8 + (size_t)s3 * PS1 + co);
        int u4 = *(const unsigned short*)(t1f8 + (size_t)s4 * PS1 + co);
        int u5 = *(const unsigned short*)(t1f8 + (size_t)s5 * PS1 + co);
        int u6 = *(const unsigned short*)(t1f8 + (size_t)s6 * PS1 + co);
        int u7 = *(const unsigned short*)(t1f8 + (size_t)s7 * PS1 + co);
        acc0 += __builtin_amdgcn_cvt_f32_fp8(u0, 0); acc1 += __builtin_amdgcn_cvt_f32_fp8(u0, 1);
        acc0 += __builtin_amdgcn_cvt_f32_fp8(u1, 0); acc1 += __builtin_amdgcn_cvt_f32_fp8(u1, 1);
        acc0 += __builtin_amdgcn_cvt_f32_fp8(u2, 0); acc1 += __builtin_amdgcn_cvt_f32_fp8(u2, 1);
        acc0 += __builtin_amdgcn_cvt_f32_fp8(u3, 0); acc1 += __builtin_amdgcn_cvt_f32_fp8(u3, 1);
        acc0 += __builtin_amdgcn_cvt_f32_fp8(u4, 0); acc1 += __builtin_amdgcn_cvt_f32_fp8(u4, 1);
        acc0 += __builtin_amdgcn_cvt_f32_fp8(u5, 0); acc1 += __builtin_amdgcn_cvt_f32_fp8(u5, 1);
        acc0 += __builtin_amdgcn_cvt_f32_fp8(u6, 0); acc1 += __builtin_amdgcn_cvt_f32_fp8(u6, 1);
        acc0 += __builtin_amdgcn_cvt_f32_fp8(u7, 0); acc1 += __builtin_amdgcn_cvt_f32_fp8(u7, 1);
    }
    for (; e < m; ++e) {
        int u = *(const unsigned short*)(t1f8 + (size_t)ep[e] * PS1 + co);
        acc0 += __builtin_amdgcn_cvt_f32_fp8(u, 0);
        acc1 += __builtin_amdgcn_cvt_f32_fp8(u, 1);
    }
    if (deg > SLOT) {
        int novf = *ovfc; novf = novf < OVFCAP ? novf : OVFCAP;
        for (int j2 = 0; j2 < novf; ++j2) {
            int2 p = ovf[j2];
            if (p.x == n) {
                int u = *(const unsigned short*)(t1f8 + (size_t)p.y * PS1 + co);
                acc0 += __builtin_amdgcn_cvt_f32_fp8(u, 0);
                acc1 += __builtin_amdgcn_cvt_f32_fp8(u, 1);
            }
        }
    }
    float d = (float)(deg > 0 ? deg : 1);
    float v0 = fmaxf(acc0 / d + b1[co], 0.f);
    float v1 = fmaxf(acc1 / d + b1[co + 1], 0.f);
    h1b[(size_t)n * 50 + l] = (unsigned)f2bf(v0) | ((unsigned)f2bf(v1) << 16);
}

// ---------------- GCN layer 2 GEMM: t2b (packed bf16) = h1 @ gc2_W ----------------
__global__ void k_gemm2(const unsigned* __restrict__ h1b, const float* __restrict__ W,
                        unsigned* __restrict__ t2b) {
    __shared__ float sW[C1 * C2];
    __shared__ float sr[16][C1];
    __shared__ float sc[16][C2];
    for (int idx = threadIdx.x; idx < C1 * C2; idx += 320) sW[idx] = W[idx];
    int ln = threadIdx.x / C2, j = threadIdx.x % C2;
    int n0 = blockIdx.x * 16;
    for (int idx = threadIdx.x; idx < 16 * 50; idx += 320) {
        int r = idx / 50, c = idx % 50;
        int n = n0 + r;
        unsigned u = (n < NN) ? h1b[(size_t)n * 50 + c] : 0u;
        sr[r][2 * c] = bf_lo(u);
        sr[r][2 * c + 1] = bf_hi(u);
    }
    __syncthreads();
    if (ln < 16) {
        float acc = 0.f;
        #pragma unroll 4
        for (int k = 0; k < C1; ++k) acc += sr[ln][k] * sW[k * C2 + j];
        sc[ln][j] = acc;
    }
    __syncthreads();
    for (int idx = threadIdx.x; idx < 16 * 10; idx += 320) {
        int r = idx / 10, jp = idx % 10;
        int n = n0 + r;
        if (n < NN)
            t2b[(size_t)n * 10 + jp] =
                (unsigned)f2bf(sc[r][2 * jp]) | ((unsigned)f2bf(sc[r][2 * jp + 1]) << 16);
    }
}

// ---------------- agg2 (padded-slot mean+bias+relu) + graph pool (atomic) ----------------
__global__ void k_agg2p(const unsigned* __restrict__ t2b, const int* __restrict__ cnt,
                        const unsigned short* __restrict__ epad, const int2* __restrict__ ovf,
                        const int* __restrict__ ovfc, const float* __restrict__ bias,
                        const int* __restrict__ gid, float* __restrict__ hgs) {
    int ln = threadIdx.x / C2, c = threadIdx.x % C2;
    if (ln >= 12) return;
    int n = blockIdx.x * 12 + ln;
    if (n >= NN) return;
    const int deg = cnt[n * CSTR];
    const int m = deg < SLOT ? deg : SLOT;
    const unsigned short* ep = epad + (size_t)n * SLOT;
    const int jp = c >> 1, hi = c & 1;
    float acc = 0.f;
    int e = 0;
    for (; e + 3 < m; e += 4) {
        int s0 = ep[e], s1 = ep[e + 1], s2 = ep[e + 2], s3 = ep[e + 3];
        unsigned u0 = t2b[(size_t)s0 * 10 + jp];
        unsigned u1 = t2b[(size_t)s1 * 10 + jp];
        unsigned u2 = t2b[(size_t)s2 * 10 + jp];
        unsigned u3 = t2b[(size_t)s3 * 10 + jp];
        acc += hi ? bf_hi(u0) : bf_lo(u0);
        acc += hi ? bf_hi(u1) : bf_lo(u1);
        acc += hi ? bf_hi(u2) : bf_lo(u2);
        acc += hi ? bf_hi(u3) : bf_lo(u3);
    }
    for (; e < m; ++e) {
        unsigned u = t2b[(size_t)ep[e] * 10 + jp];
        acc += hi ? bf_hi(u) : bf_lo(u);
    }
    if (deg > SLOT) {
        int novf = *ovfc; novf = novf < OVFCAP ? novf : OVFCAP;
        for (int j2 = 0; j2 < novf; ++j2) {
            int2 p = ovf[j2];
            if (p.x == n) {
                unsigned u = t2b[(size_t)p.y * 10 + jp];
                acc += hi ? bf_hi(u) : bf_lo(u);
            }
        }
    }
    float d = (float)(deg > 0 ? deg : 1);
    float v = acc / d + bias[c];
    v = v > 0.f ? v : 0.f;
    atomicAdd(&hgs[gid[n] * C2 + c], v);
}

// ---------------- merged per-graph tail: hg div + attn head + fc1b (o1 write) ----------------
__global__ __launch_bounds__(128) void k_hfc1(const float* __restrict__ hgs,
                                              const int* __restrict__ gid,
                                              const float* __restrict__ desc2d,
                                              const float* __restrict__ pgW,
                                              const float* __restrict__ pgb,
                                              const float* __restrict__ p2W,
                                              const float* __restrict__ p2b,
                                              const float* __restrict__ W2,
                                              const float* __restrict__ V,
                                              const float* __restrict__ W1,
                                              float* __restrict__ o1) {
    __shared__ float shg[C2];
    __shared__ float sg[DHH];
    __shared__ float sa;
    const int b = blockIdx.x, tid = threadIdx.x;
    if (tid < C2) {
        int lo = 0, hi = NN;
        while (lo < hi) { int m = (lo + hi) >> 1; if (gid[m] < b) lo = m + 1; else hi = m; }
        int lo2 = lo, hi2 = NN;
        while (lo2 < hi2) { int m = (lo2 + hi2) >> 1; if (gid[m] < b + 1) lo2 = m + 1; else hi2 = m; }
        float dcnt = (float)(lo2 - lo);
        if (dcnt < 1.f) dcnt = 1.f;
        shg[tid] = hgs[b * C2 + tid] / dcnt;
    }
    __syncthreads();
    float hdj = 0.f;
    if (tid < DHH) {
        float hgj = pgb[tid];
        #pragma unroll
        for (int k = 0; k < C2; ++k) hgj += shg[k] * pgW[k * DHH + tid];
        hdj = p2b[tid];
        #pragma unroll 4
        for (int k = 0; k < DD2; ++k) hdj += desc2d[b * DD2 + k] * p2W[k * DHH + tid];
        sg[tid] = hgj;
    }
    __syncthreads();
    if (tid < DHH) {
        float tj = 0.f;
        #pragma unroll 4
        for (int k = 0; k < DHH; ++k) tj += sg[k] * W2[k * DHH + tid];
        float v = tj * hdj;
        #pragma unroll
        for (int off = 32; off; off >>= 1) v += __shfl_xor(v, off, 64);
        if (tid == 0) sa = 1.f / (1.f + expf(-v));
    }
    __syncthreads();
    const int j = tid;   // 0..127
    const float* Vb = V + (size_t)b * NU + j;
    const float* WL = W1 + (size_t)200 * HH1 + j;
    float sv = Vb[20 * HH1];
    float sw = WL[(size_t)20 * KD * HH1];
    #pragma unroll
    for (int i = 0; i < 20; ++i) {
        float h = shg[i];
        sv += h * Vb[i * HH1];
        sw += h * WL[(size_t)i * KD * HH1];
    }
    o1[b * HH1 + j] = sa * sv + sw;
}

// ---------------- fc2 with in-block bn1 stats ----------------
__global__ __launch_bounds__(128) void k_fc2s(const float* __restrict__ o1,
                                              const float* __restrict__ g,
                                              const float* __restrict__ beta,
                                              const float* __restrict__ W,
                                              float* __restrict__ o2) {
    __shared__ float r[HH1];
    __shared__ float part[4][HH2];
    const int tid = threadIdx.x;   // 128
    float s = 0.f, s2 = 0.f;
    for (int b = 0; b < NB; ++b) {
        float v = o1[b * HH1 + tid];
        s += v; s2 += v * v;
    }
    float mu = s / NB;
    float rstd = rsqrtf(s2 / NB - mu * mu + 1e-5f);
    float scale = rstd * g[tid];
    float shift = beta[tid] - mu * scale;
    const int m = tid & 31, p = tid >> 5;
    for (int q = 0; q < 4; ++q) {
        int b = blockIdx.x * 4 + q;
        float v = o1[b * HH1 + tid];
        __syncthreads();
        r[tid] = fmaxf(v * scale + shift, 0.f);
        __syncthreads();
        float acc = 0.f;
        #pragma unroll 4
        for (int j = p * 32; j < p * 32 + 32; ++j) acc += r[j] * W[j * HH2 + m];
        part[p][m] = acc;
        __syncthreads();
        if (tid < HH2) o2[b * HH2 + tid] = part[0][tid] + part[1][tid] + part[2][tid] + part[3][tid];
    }
}

// ---------------- final: in-block bn2 stats + relu + fc3 ----------------
__global__ __launch_bounds__(512) void k_finals(const float* __restrict__ o2,
                                                const float* __restrict__ g,
                                                const float* __restrict__ beta,
                                                const float* __restrict__ W3,
                                                const float* __restrict__ b3,
                                                float* __restrict__ out) {
    __shared__ float ps[16][HH2], ps2[16][HH2];
    __shared__ float sscale[HH2], sshift[HH2];
    const int tid = threadIdx.x;    // 512
    const int gq = tid >> 5, m = tid & 31;
    float s = 0.f, s2 = 0.f;
    for (int rr = 0; rr < 32; ++rr) {
        float v = o2[(gq * 32 + rr) * HH2 + m];
        s += v; s2 += v * v;
    }
    ps[gq][m] = s; ps2[gq][m] = s2;
    __syncthreads();
    if (tid < HH2) {
        float ts = 0.f, ts2 = 0.f;
        #pragma unroll
        for (int q = 0; q < 16; ++q) { ts += ps[q][tid]; ts2 += ps2[q][tid]; }
        float mu = ts / NB;
        float rstd = rsqrtf(ts2 / NB - mu * mu + 1e-5f);
        float scale = rstd * g[tid];
        sscale[tid] = scale;
        sshift[tid] = beta[tid] - mu * scale;
    }
    __syncthreads();
    float acc = b3[0];
    #pragma unroll 4
    for (int mm = 0; mm < HH2; ++mm) {
        float v = o2[tid * HH2 + mm];
        acc += fmaxf(v * sscale[mm] + sshift[mm], 0.f) * W3[mm];
    }
    out[tid] = acc;
}

extern "C" void kernel_launch(void* const* d_in, const int* in_sizes, int n_in,
                              void* d_out, int out_size, void* d_ws, size_t ws_size,
                              hipStream_t stream) {
    const float* feat   = (const float*)d_in[0];
    const float* desc2d = (const float*)d_in[1];
    const float* gc1W = (const float*)d_in[3];
    const float* gc1b = (const float*)d_in[4];
    const float* gc2W = (const float*)d_in[5];
    const float* gc2b = (const float*)d_in[6];
    const float* pgW  = (const float*)d_in[7];
    const float* pgb  = (const float*)d_in[8];
    const float* p2W  = (const float*)d_in[9];
    const float* p2b  = (const float*)d_in[10];
    const float* W2   = (const float*)d_in[11];
    const float* fc1W = (const float*)d_in[12];
    const float* fc2W = (const float*)d_in[14];
    const float* fc3W = (const float*)d_in[16];
    const float* fc3b = (const float*)d_in[17];
    const float* bn1g = (const float*)d_in[18];
    const float* bn1b = (const float*)d_in[19];
    const float* bn2g = (const float*)d_in[20];
    const float* bn2b = (const float*)d_in[21];
    const int* src = (const int*)d_in[22];
    const int* dst = (const int*)d_in[23];
    const int* gid = (const int*)d_in[24];
    float* out = (float*)d_out;

    char* ws = (char*)d_ws;
    size_t off = 0;
    auto alloc = [&](size_t nb) {
        void* p = ws + off;
        off = (off + nb + 255) & ~(size_t)255;
        return p;
    };
    unsigned char* t1f8 = (unsigned char*)alloc((size_t)NN * PS1);   // 6.4 MB fp8
    unsigned* h1b = (unsigned*)alloc((size_t)NN * 50 * 4);           // 10 MB packed bf16
    unsigned* t2b = (unsigned*)alloc((size_t)NN * 10 * 4);           // 2 MB packed bf16
    int* cnt_in  = (int*)alloc((size_t)NN * CSTR * 4);               // 3.2 MB line-padded
    int* pos     = (int*)alloc((size_t)NE * 4);
    unsigned short* epad = (unsigned short*)alloc((size_t)NN * SLOT * 2);  // 3.2 MB u16
    int2* ovf    = (int2*)alloc((size_t)OVFCAP * 8);
    int* ovfc    = (int*)alloc(256);
    unsigned short* Bf = (unsigned short*)alloc((size_t)NCT * 4 * 64 * 16);  // 28 KB
    float* V     = (float*)alloc((size_t)NB * NU * 4);               // 5.5 MB
    float* hgs   = (float*)alloc((size_t)NB * C2 * 4);
    float* o1    = (float*)alloc((size_t)NB * HH1 * 4);
    float* o2    = (float*)alloc((size_t)NB * HH2 * 4);

    k_packB_init<<<SCB, 256, 0, stream>>>(gc1W, Bf, cnt_in, hgs, ovfc);
    k_front<<<GB1 + FCB + FPB, 256, 0, stream>>>(feat, Bf, t1f8, dst, cnt_in, pos,
                                                 desc2d, fc1W, V);
    k_scat<<<(NE + 255) / 256, 256, 0, stream>>>(src, dst, pos, epad, ovf, ovfc);

    k_agg1<<<(NN + 3) / 4, 256, 0, stream>>>(t1f8, cnt_in, epad, ovf, ovfc, gc1b, h1b);
    k_gemm2<<<(NN + 15) / 16, 320, 0, stream>>>(h1b, gc2W, t2b);
    k_agg2p<<<(NN + 11) / 12, 256, 0, stream>>>(t2b, cnt_in, epad, ovf, ovfc, gc2b, gid, hgs);

    k_hfc1<<<NB, 128, 0, stream>>>(hgs, gid, desc2d, pgW, pgb, p2W, p2b, W2, V, fc1W, o1);
    k_fc2s<<<NB / 4, 128, 0, stream>>>(o1, bn1g, bn1b, fc2W, o2);
    k_finals<<<1, 512, 0, stream>>>(o2, bn2g, bn2b, fc3W, fc3b, out);
}

// Round 21
// 182.594 us; speedup vs baseline: 4.0654x; 1.0030x over previous
//
#include <hip/hip_runtime.h>

#define NN 50000
#define NE 800000
#define NB 512
#define DIN 128
#define DD2 200
#define C1 100
#define C2 20
#define DHH 64
#define HH1 128
#define HH2 32
#define KD 201      // fusion inner dim per i (200 + 1)
#define KDP 204     // padded LDS row stride
#define NU 2688     // 21 * 128
#define SCB 196     // init blocks
#define NCT 7       // col tiles of 16 covering 100
#define NTILE 3125  // 50000 / 16 row tiles
#define GB1 782     // gemm1 blocks in k_front
#define FPB 3125    // fill blocks in k_front
#define FCB 672     // fc1V blocks in k_front
#define PS1 128     // t1 fp8 row stride (bytes)
#define SLOT 32     // padded edge slots per node (u16) -> 64B/node index row
#define OVFCAP 8192
#define CSTR 16     // cnt stride (ints) -> one counter per 64B line

typedef short sh8 __attribute__((ext_vector_type(8)));
typedef float f32x4 __attribute__((ext_vector_type(4)));

__device__ __forceinline__ unsigned short f2bf(float x) {
    unsigned u = __float_as_uint(x);
    unsigned r = (u + 0x7fffu + ((u >> 16) & 1u)) >> 16;   // RNE
    return (unsigned short)r;
}
__device__ __forceinline__ float bf_lo(unsigned u) { return __uint_as_float(u << 16); }
__device__ __forceinline__ float bf_hi(unsigned u) { return __uint_as_float(u & 0xffff0000u); }

// ---------------- init: pack gc1_W into B-fragments + zero cnt(padded)/hgs/ovfc ----------------
__global__ void k_packB_init(const float* __restrict__ W, unsigned short* __restrict__ Bf,
                             int* __restrict__ cnt, float* __restrict__ hgs,
                             int* __restrict__ ovfc) {
    int idx = blockIdx.x * 256 + threadIdx.x;
    if (idx < NCT * 4 * 64) {
        int lane = idx & 63;
        int kc = (idx >> 6) & 3;
        int ct = idx >> 8;
        int col = ct * 16 + (lane & 15);
        int k0 = kc * 32 + (lane >> 4) * 8;
        unsigned short* outp = Bf + (size_t)idx * 8;
        #pragma unroll
        for (int e = 0; e < 8; ++e) {
            float v = (col < C1) ? W[(k0 + e) * C1 + col] : 0.f;
            outp[e] = f2bf(v);
        }
    }
    for (int i = idx; i < NN * CSTR; i += SCB * 256) cnt[i] = 0;
    if (idx < NB * C2) hgs[idx] = 0.f;
    if (idx == 0) *ovfc = 0;
}

// ---------------- fused front: gemm1 || fc1V || fill+scatter (compute segments first) ----------------
__global__ __launch_bounds__(256) void k_front(const float* __restrict__ feat,
                                               const unsigned short* __restrict__ Bf,
                                               unsigned char* __restrict__ t1f8,
                                               const int* __restrict__ src,
                                               const int* __restrict__ dst,
                                               int* __restrict__ cnt,
                                               unsigned short* __restrict__ epad,
                                               int2* __restrict__ ovf,
                                               int* __restrict__ ovfc,
                                               const float* __restrict__ desc2d,
                                               const float* __restrict__ W1,
                                               float* __restrict__ V) {
    __shared__ float smem[7168];         // 28 KB, shared by gemm1 (sB) and fc1V (S)
    const int tid = threadIdx.x;

    if (blockIdx.x >= GB1 + FCB) {
        // ---- fill + direct scatter: one atomic pass; epad row = one 64B line ----
        int e = (blockIdx.x - GB1 - FCB) * 256 + tid;
        if (e < NE) {
            int d = dst[e], s = src[e];
            int slot = atomicAdd(&cnt[d * CSTR], 1);
            if (slot < SLOT) {
                epad[(size_t)d * SLOT + slot] = (unsigned short)s;
            } else {
                int o = atomicAdd(ovfc, 1);
                if (o < OVFCAP) ovf[o] = make_int2(d, s);
            }
        }
        return;
    }

    if (blockIdx.x < GB1) {
        // ---- gemm1 via MFMA ----
        sh8* sB = (sh8*)smem;            // [NCT][4][64]
        {
            const uint4* srcp = (const uint4*)Bf;
            uint4* dstp = (uint4*)smem;
            for (int i = tid; i < NCT * 4 * 64; i += 256) dstp[i] = srcp[i];
        }
        __syncthreads();
        const int w = tid >> 6, lane = tid & 63;
        const int ri = lane & 15;
        const int kg = lane >> 4;
        int tile = blockIdx.x * 4 + w;
        if (tile < NTILE) {
            const int n = tile * 16 + ri;
            f32x4 acc[NCT];
            #pragma unroll
            for (int ct = 0; ct < NCT; ++ct) acc[ct] = (f32x4){0.f, 0.f, 0.f, 0.f};
            #pragma unroll
            for (int kc = 0; kc < 4; ++kc) {
                const float* ap = feat + (size_t)n * DIN + kc * 32 + kg * 8;
                float4 a0 = *(const float4*)ap;
                float4 a1 = *(const float4*)(ap + 4);
                union { sh8 v; unsigned short u[8]; } af;
                af.u[0] = f2bf(a0.x); af.u[1] = f2bf(a0.y);
                af.u[2] = f2bf(a0.z); af.u[3] = f2bf(a0.w);
                af.u[4] = f2bf(a1.x); af.u[5] = f2bf(a1.y);
                af.u[6] = f2bf(a1.z); af.u[7] = f2bf(a1.w);
                #pragma unroll
                for (int ct = 0; ct < NCT; ++ct)
                    acc[ct] = __builtin_amdgcn_mfma_f32_16x16x32_bf16(
                        af.v, sB[(ct * 4 + kc) * 64 + lane], acc[ct], 0, 0, 0);
            }
            const int rbase = tile * 16 + kg * 4;
            #pragma unroll
            for (int ct = 0; ct < NCT; ++ct) {
                int col = ct * 16 + ri;
                if (col < C1) {
                    #pragma unroll
                    for (int r = 0; r < 4; ++r) {
                        int pk = __builtin_amdgcn_cvt_pk_fp8_f32(acc[ct][r], acc[ct][r], 0, false);
                        t1f8[(size_t)(rbase + r) * PS1 + col] = (unsigned char)(pk & 0xFF);
                    }
                }
            }
        }
        return;
    }

    // ---- fc1V: V[b][i*128+j] = sum_{k<200} desc2d[b][k] * W1[(i*201+k)*128+j] ----
    {
        float (*S)[KDP] = (float(*)[KDP])smem;   // [32][204]
        int fid = blockIdx.x - GB1;              // 0..671
        const int i = fid / 32;
        const int rem = fid % 32;
        const int bt = rem >> 1;
        const int half = rem & 1;
        for (int idx = tid; idx < 32 * 50; idx += 256) {
            int r = idx / 50, c4 = idx % 50;
            *(float4*)&S[r][c4 * 4] =
                *(const float4*)(desc2d + (size_t)(bt * 32 + r) * DD2 + c4 * 4);
        }
        __syncthreads();
        const int c = tid & 31;
        const int rg = tid >> 5;
        float acc[4][2];
        #pragma unroll
        for (int r = 0; r < 4; ++r) { acc[r][0] = 0.f; acc[r][1] = 0.f; }
        const float* Wb = W1 + (size_t)i * (KD * HH1) + half * 64 + c;
        for (int k = 0; k < 200; k += 4) {
            const float* Wk = Wb + (size_t)k * HH1;
            float w0[2], w1[2], w2[2], w3[2];
            #pragma unroll
            for (int m = 0; m < 2; ++m) {
                w0[m] = Wk[32 * m];
                w1[m] = Wk[HH1 + 32 * m];
                w2[m] = Wk[2 * HH1 + 32 * m];
                w3[m] = Wk[3 * HH1 + 32 * m];
            }
            #pragma unroll
            for (int r = 0; r < 4; ++r) {
                float4 a4 = *(const float4*)&S[rg * 4 + r][k];
                #pragma unroll
                for (int m = 0; m < 2; ++m)
                    acc[r][m] += a4.x * w0[m] + a4.y * w1[m] + a4.z * w2[m] + a4.w * w3[m];
            }
        }
        #pragma unroll
        for (int r = 0; r < 4; ++r) {
            int b = bt * 32 + rg * 4 + r;
            float* Vr = V + (size_t)b * NU + i * HH1 + half * 64 + c;
            Vr[0] = acc[r][0];
            Vr[32] = acc[r][1];
        }
    }
}

// ---------------- agg1: fp8 padded-slot gather-mean + bias + relu -> packed bf16 h1b ----------------
__global__ __launch_bounds__(256) void k_agg1(const unsigned char* __restrict__ t1f8,
                                              const int* __restrict__ cnt,
                                              const unsigned short* __restrict__ epad,
                                              const int2* __restrict__ ovf,
                                              const int* __restrict__ ovfc,
                                              const float* __restrict__ b1,
                                              unsigned* __restrict__ h1b) {
    const int tid = threadIdx.x;
    const int w = tid >> 6, l = tid & 63;
    const int n = blockIdx.x * 4 + w;
    if (n >= NN || l >= 50) return;
    const int deg = cnt[n * CSTR];
    const int m = deg < SLOT ? deg : SLOT;
    const unsigned short* ep = epad + (size_t)n * SLOT;
    const int co = 2 * l;
    float acc0 = 0.f, acc1 = 0.f;
    int e = 0;
    for (; e + 7 < m; e += 8) {
        int s0 = ep[e],     s1 = ep[e + 1], s2 = ep[e + 2], s3 = ep[e + 3];
        int s4 = ep[e + 4], s5 = ep[e + 5], s6 = ep[e + 6], s7 = ep[e + 7];
        int u0 = *(const unsigned short*)(t1f8 + (size_t)s0 * PS1 + co);
        int u1 = *(const unsigned short*)(t1f8 + (size_t)s1 * PS1 + co);
        int u2 = *(const unsigned short*)(t1f8 + (size_t)s2 * PS1 + co);
        int u3 = *(const unsigned short*)(t1f8 + (size_t)s3 * PS1 + co);
        int u4 = *(const unsigned short*)(t1f8 + (size_t)s4 * PS1 + co);
        int u5 = *(const unsigned short*)(t1f8 + (size_t)s5 * PS1 + co);
        int u6 = *(const unsigned short*)(t1f8 + (size_t)s6 * PS1 + co);
        int u7 = *(const unsigned short*)(t1f8 + (size_t)s7 * PS1 + co);
        acc0 += __builtin_amdgcn_cvt_f32_fp8(u0, 0); acc1 += __builtin_amdgcn_cvt_f32_fp8(u0, 1);
        acc0 += __builtin_amdgcn_cvt_f32_fp8(u1, 0); acc1 += __builtin_amdgcn_cvt_f32_fp8(u1, 1);
        acc0 += __builtin_amdgcn_cvt_f32_fp8(u2, 0); acc1 += __builtin_amdgcn_cvt_f32_fp8(u2, 1);
        acc0 += __builtin_amdgcn_cvt_f32_fp8(u3, 0); acc1 += __builtin_amdgcn_cvt_f32_fp8(u3, 1);
        acc0 += __builtin_amdgcn_cvt_f32_fp8(u4, 0); acc1 += __builtin_amdgcn_cvt_f32_fp8(u4, 1);
        acc0 += __builtin_amdgcn_cvt_f32_fp8(u5, 0); acc1 += __builtin_amdgcn_cvt_f32_fp8(u5, 1);
        acc0 += __builtin_amdgcn_cvt_f32_fp8(u6, 0); acc1 += __builtin_amdgcn_cvt_f32_fp8(u6, 1);
        acc0 += __builtin_amdgcn_cvt_f32_fp8(u7, 0); acc1 += __builtin_amdgcn_cvt_f32_fp8(u7, 1);
    }
    for (; e < m; ++e) {
        int u = *(const unsigned short*)(t1f8 + (size_t)ep[e] * PS1 + co);
        acc0 += __builtin_amdgcn_cvt_f32_fp8(u, 0);
        acc1 += __builtin_amdgcn_cvt_f32_fp8(u, 1);
    }
    if (deg > SLOT) {
        int novf = *ovfc; novf = novf < OVFCAP ? novf : OVFCAP;
        for (int j2 = 0; j2 < novf; ++j2) {
            int2 p = ovf[j2];
            if (p.x == n) {
                int u = *(const unsigned short*)(t1f8 + (size_t)p.y * PS1 + co);
                acc0 += __builtin_amdgcn_cvt_f32_fp8(u, 0);
                acc1 += __builtin_amdgcn_cvt_f32_fp8(u, 1);
            }
        }
    }
    float d = (float)(deg > 0 ? deg : 1);
    float v0 = fmaxf(acc0 / d + b1[co], 0.f);
    float v1 = fmaxf(acc1 / d + b1[co + 1], 0.f);
    h1b[(size_t)n * 50 + l] = (unsigned)f2bf(v0) | ((unsigned)f2bf(v1) << 16);
}

// ---------------- GCN layer 2 GEMM: t2b (packed bf16) = h1 @ gc2_W ----------------
__global__ void k_gemm2(const unsigned* __restrict__ h1b, const float* __restrict__ W,
                        unsigned* __restrict__ t2b) {
    __shared__ float sW[C1 * C2];
    __shared__ float sr[16][C1];
    __shared__ float sc[16][C2];
    for (int idx = threadIdx.x; idx < C1 * C2; idx += 320) sW[idx] = W[idx];
    int ln = threadIdx.x / C2, j = threadIdx.x % C2;
    int n0 = blockIdx.x * 16;
    for (int idx = threadIdx.x; idx < 16 * 50; idx += 320) {
        int r = idx / 50, c = idx % 50;
        int n = n0 + r;
        unsigned u = (n < NN) ? h1b[(size_t)n * 50 + c] : 0u;
        sr[r][2 * c] = bf_lo(u);
        sr[r][2 * c + 1] = bf_hi(u);
    }
    __syncthreads();
    if (ln < 16) {
        float acc = 0.f;
        #pragma unroll 4
        for (int k = 0; k < C1; ++k) acc += sr[ln][k] * sW[k * C2 + j];
        sc[ln][j] = acc;
    }
    __syncthreads();
    for (int idx = threadIdx.x; idx < 16 * 10; idx += 320) {
        int r = idx / 10, jp = idx % 10;
        int n = n0 + r;
        if (n < NN)
            t2b[(size_t)n * 10 + jp] =
                (unsigned)f2bf(sc[r][2 * jp]) | ((unsigned)f2bf(sc[r][2 * jp + 1]) << 16);
    }
}

// ---------------- agg2 (padded-slot mean+bias+relu) + graph pool (atomic) ----------------
__global__ void k_agg2p(const unsigned* __restrict__ t2b, const int* __restrict__ cnt,
                        const unsigned short* __restrict__ epad, const int2* __restrict__ ovf,
                        const int* __restrict__ ovfc, const float* __restrict__ bias,
                        const int* __restrict__ gid, float* __restrict__ hgs) {
    int ln = threadIdx.x / C2, c = threadIdx.x % C2;
    if (ln >= 12) return;
    int n = blockIdx.x * 12 + ln;
    if (n >= NN) return;
    const int deg = cnt[n * CSTR];
    const int m = deg < SLOT ? deg : SLOT;
    const unsigned short* ep = epad + (size_t)n * SLOT;
    const int jp = c >> 1, hi = c & 1;
    float acc = 0.f;
    int e = 0;
    for (; e + 3 < m; e += 4) {
        int s0 = ep[e], s1 = ep[e + 1], s2 = ep[e + 2], s3 = ep[e + 3];
        unsigned u0 = t2b[(size_t)s0 * 10 + jp];
        unsigned u1 = t2b[(size_t)s1 * 10 + jp];
        unsigned u2 = t2b[(size_t)s2 * 10 + jp];
        unsigned u3 = t2b[(size_t)s3 * 10 + jp];
        acc += hi ? bf_hi(u0) : bf_lo(u0);
        acc += hi ? bf_hi(u1) : bf_lo(u1);
        acc += hi ? bf_hi(u2) : bf_lo(u2);
        acc += hi ? bf_hi(u3) : bf_lo(u3);
    }
    for (; e < m; ++e) {
        unsigned u = t2b[(size_t)ep[e] * 10 + jp];
        acc += hi ? bf_hi(u) : bf_lo(u);
    }
    if (deg > SLOT) {
        int novf = *ovfc; novf = novf < OVFCAP ? novf : OVFCAP;
        for (int j2 = 0; j2 < novf; ++j2) {
            int2 p = ovf[j2];
            if (p.x == n) {
                unsigned u = t2b[(size_t)p.y * 10 + jp];
                acc += hi ? bf_hi(u) : bf_lo(u);
            }
        }
    }
    float d = (float)(deg > 0 ? deg : 1);
    float v = acc / d + bias[c];
    v = v > 0.f ? v : 0.f;
    atomicAdd(&hgs[gid[n] * C2 + c], v);
}

// ---------------- merged per-graph tail: hg div + attn head + fc1b (o1 write) ----------------
__global__ __launch_bounds__(128) void k_hfc1(const float* __restrict__ hgs,
                                              const int* __restrict__ gid,
                                              const float* __restrict__ desc2d,
                                              const float* __restrict__ pgW,
                                              const float* __restrict__ pgb,
                                              const float* __restrict__ p2W,
                                              const float* __restrict__ p2b,
                                              const float* __restrict__ W2,
                                              const float* __restrict__ V,
                                              const float* __restrict__ W1,
                                              float* __restrict__ o1) {
    __shared__ float shg[C2];
    __shared__ float sg[DHH];
    __shared__ float sa;
    const int b = blockIdx.x, tid = threadIdx.x;
    if (tid < C2) {
        int lo = 0, hi = NN;
        while (lo < hi) { int m = (lo + hi) >> 1; if (gid[m] < b) lo = m + 1; else hi = m; }
        int lo2 = lo, hi2 = NN;
        while (lo2 < hi2) { int m = (lo2 + hi2) >> 1; if (gid[m] < b + 1) lo2 = m + 1; else hi2 = m; }
        float dcnt = (float)(lo2 - lo);
        if (dcnt < 1.f) dcnt = 1.f;
        shg[tid] = hgs[b * C2 + tid] / dcnt;
    }
    __syncthreads();
    float hdj = 0.f;
    if (tid < DHH) {
        float hgj = pgb[tid];
        #pragma unroll
        for (int k = 0; k < C2; ++k) hgj += shg[k] * pgW[k * DHH + tid];
        hdj = p2b[tid];
        #pragma unroll 4
        for (int k = 0; k < DD2; ++k) hdj += desc2d[b * DD2 + k] * p2W[k * DHH + tid];
        sg[tid] = hgj;
    }
    __syncthreads();
    if (tid < DHH) {
        float tj = 0.f;
        #pragma unroll 4
        for (int k = 0; k < DHH; ++k) tj += sg[k] * W2[k * DHH + tid];
        float v = tj * hdj;
        #pragma unroll
        for (int off = 32; off; off >>= 1) v += __shfl_xor(v, off, 64);
        if (tid == 0) sa = 1.f / (1.f + expf(-v));
    }
    __syncthreads();
    const int j = tid;   // 0..127
    const float* Vb = V + (size_t)b * NU + j;
    const float* WL = W1 + (size_t)200 * HH1 + j;
    float sv = Vb[20 * HH1];
    float sw = WL[(size_t)20 * KD * HH1];
    #pragma unroll
    for (int i = 0; i < 20; ++i) {
        float h = shg[i];
        sv += h * Vb[i * HH1];
        sw += h * WL[(size_t)i * KD * HH1];
    }
    o1[b * HH1 + j] = sa * sv + sw;
}

// ---------------- fc2 with in-block bn1 stats ----------------
__global__ __launch_bounds__(128) void k_fc2s(const float* __restrict__ o1,
                                              const float* __restrict__ g,
                                              const float* __restrict__ beta,
                                              const float* __restrict__ W,
                                              float* __restrict__ o2) {
    __shared__ float r[HH1];
    __shared__ float part[4][HH2];
    const int tid = threadIdx.x;   // 128
    float s = 0.f, s2 = 0.f;
    for (int b = 0; b < NB; ++b) {
        float v = o1[b * HH1 + tid];
        s += v; s2 += v * v;
    }
    float mu = s / NB;
    float rstd = rsqrtf(s2 / NB - mu * mu + 1e-5f);
    float scale = rstd * g[tid];
    float shift = beta[tid] - mu * scale;
    const int m = tid & 31, p = tid >> 5;
    for (int q = 0; q < 4; ++q) {
        int b = blockIdx.x * 4 + q;
        float v = o1[b * HH1 + tid];
        __syncthreads();
        r[tid] = fmaxf(v * scale + shift, 0.f);
        __syncthreads();
        float acc = 0.f;
        #pragma unroll 4
        for (int j = p * 32; j < p * 32 + 32; ++j) acc += r[j] * W[j * HH2 + m];
        part[p][m] = acc;
        __syncthreads();
        if (tid < HH2) o2[b * HH2 + tid] = part[0][tid] + part[1][tid] + part[2][tid] + part[3][tid];
    }
}

// ---------------- final: in-block bn2 stats + relu + fc3 ----------------
__global__ __launch_bounds__(512) void k_finals(const float* __restrict__ o2,
                                                const float* __restrict__ g,
                                                const float* __restrict__ beta,
                                                const float* __restrict__ W3,
                                                const float* __restrict__ b3,
                                                float* __restrict__ out) {
    __shared__ float ps[16][HH2], ps2[16][HH2];
    __shared__ float sscale[HH2], sshift[HH2];
    const int tid = threadIdx.x;    // 512
    const int gq = tid >> 5, m = tid & 31;
    float s = 0.f, s2 = 0.f;
    for (int rr = 0; rr < 32; ++rr) {
        float v = o2[(gq * 32 + rr) * HH2 + m];
        s += v; s2 += v * v;
    }
    ps[gq][m] = s; ps2[gq][m] = s2;
    __syncthreads();
    if (tid < HH2) {
        float ts = 0.f, ts2 = 0.f;
        #pragma unroll
        for (int q = 0; q < 16; ++q) { ts += ps[q][tid]; ts2 += ps2[q][tid]; }
        float mu = ts / NB;
        float rstd = rsqrtf(ts2 / NB - mu * mu + 1e-5f);
        float scale = rstd * g[tid];
        sscale[tid] = scale;
        sshift[tid] = beta[tid] - mu * scale;
    }
    __syncthreads();
    float acc = b3[0];
    #pragma unroll 4
    for (int mm = 0; mm < HH2; ++mm) {
        float v = o2[tid * HH2 + mm];
        acc += fmaxf(v * sscale[mm] + sshift[mm], 0.f) * W3[mm];
    }
    out[tid] = acc;
}

extern "C" void kernel_launch(void* const* d_in, const int* in_sizes, int n_in,
                              void* d_out, int out_size, void* d_ws, size_t ws_size,
                              hipStream_t stream) {
    const float* feat   = (const float*)d_in[0];
    const float* desc2d = (const float*)d_in[1];
    const float* gc1W = (const float*)d_in[3];
    const float* gc1b = (const float*)d_in[4];
    const float* gc2W = (const float*)d_in[5];
    const float* gc2b = (const float*)d_in[6];
    const float* pgW  = (const float*)d_in[7];
    const float* pgb  = (const float*)d_in[8];
    const float* p2W  = (const float*)d_in[9];
    const float* p2b  = (const float*)d_in[10];
    const float* W2   = (const float*)d_in[11];
    const float* fc1W = (const float*)d_in[12];
    const float* fc2W = (const float*)d_in[14];
    const float* fc3W = (const float*)d_in[16];
    const float* fc3b = (const float*)d_in[17];
    const float* bn1g = (const float*)d_in[18];
    const float* bn1b = (const float*)d_in[19];
    const float* bn2g = (const float*)d_in[20];
    const float* bn2b = (const float*)d_in[21];
    const int* src = (const int*)d_in[22];
    const int* dst = (const int*)d_in[23];
    const int* gid = (const int*)d_in[24];
    float* out = (float*)d_out;

    char* ws = (char*)d_ws;
    size_t off = 0;
    auto alloc = [&](size_t nb) {
        void* p = ws + off;
        off = (off + nb + 255) & ~(size_t)255;
        return p;
    };
    unsigned char* t1f8 = (unsigned char*)alloc((size_t)NN * PS1);   // 6.4 MB fp8
    unsigned* h1b = (unsigned*)alloc((size_t)NN * 50 * 4);           // 10 MB packed bf16
    unsigned* t2b = (unsigned*)alloc((size_t)NN * 10 * 4);           // 2 MB packed bf16
    int* cnt_in  = (int*)alloc((size_t)NN * CSTR * 4);               // 3.2 MB line-padded
    unsigned short* epad = (unsigned short*)alloc((size_t)NN * SLOT * 2);  // 3.2 MB u16
    int2* ovf    = (int2*)alloc((size_t)OVFCAP * 8);
    int* ovfc    = (int*)alloc(256);
    unsigned short* Bf = (unsigned short*)alloc((size_t)NCT * 4 * 64 * 16);  // 28 KB
    float* V     = (float*)alloc((size_t)NB * NU * 4);               // 5.5 MB
    float* hgs   = (float*)alloc((size_t)NB * C2 * 4);
    float* o1    = (float*)alloc((size_t)NB * HH1 * 4);
    float* o2    = (float*)alloc((size_t)NB * HH2 * 4);

    k_packB_init<<<SCB, 256, 0, stream>>>(gc1W, Bf, cnt_in, hgs, ovfc);
    k_front<<<GB1 + FCB + FPB, 256, 0, stream>>>(feat, Bf, t1f8, src, dst, cnt_in,
                                                 epad, ovf, ovfc, desc2d, fc1W, V);

    k_agg1<<<(NN + 3) / 4, 256, 0, stream>>>(t1f8, cnt_in, epad, ovf, ovfc, gc1b, h1b);
    k_gemm2<<<(NN + 15) / 16, 320, 0, stream>>>(h1b, gc2W, t2b);
    k_agg2p<<<(NN + 11) / 12, 256, 0, stream>>>(t2b, cnt_in, epad, ovf, ovfc, gc2b, gid, hgs);

    k_hfc1<<<NB, 128, 0, stream>>>(hgs, gid, desc2d, pgW, pgb, p2W, p2b, W2, V, fc1W, o1);
    k_fc2s<<<NB / 4, 128, 0, stream>>>(o1, bn1g, bn1b, fc2W, o2);
    k_finals<<<1, 512, 0, stream>>>(o2, bn2g, bn2b, fc3W, fc3b, out);
}

// Round 22
// 182.476 us; speedup vs baseline: 4.0680x; 1.0006x over previous
//
#include <hip/hip_runtime.h>

#define NN 50000
#define NE 800000
#define NB 512
#define DIN 128
#define DD2 200
#define C1 100
#define C2 20
#define DHH 64
#define HH1 128
#define HH2 32
#define KD 201      // fusion inner dim per i (200 + 1)
#define KDP 204     // padded LDS row stride
#define NU 2688     // 21 * 128
#define SCB 196     // init blocks
#define NCT 7       // col tiles of 16 covering 100
#define NTILE 3125  // 50000 / 16 row tiles
#define GB1 782     // gemm1 blocks in k_front
#define FPB 3125    // fill blocks in k_front
#define FCB 672     // fc1V blocks in k_front
#define PS1 128     // t1 fp8 row stride (bytes)
#define SLOT 32     // padded edge slots per node (u16) -> 64B/node index row
#define OVFCAP 8192
#define CSTR 16     // cnt stride (ints) -> one counter per 64B line

typedef short sh8 __attribute__((ext_vector_type(8)));
typedef float f32x4 __attribute__((ext_vector_type(4)));

__device__ __forceinline__ unsigned short f2bf(float x) {
    unsigned u = __float_as_uint(x);
    unsigned r = (u + 0x7fffu + ((u >> 16) & 1u)) >> 16;   // RNE
    return (unsigned short)r;
}
__device__ __forceinline__ float bf_lo(unsigned u) { return __uint_as_float(u << 16); }
__device__ __forceinline__ float bf_hi(unsigned u) { return __uint_as_float(u & 0xffff0000u); }

// ---------------- init: pack gc1_W into B-fragments + zero cnt(padded)/hgs/ovfc ----------------
__global__ void k_packB_init(const float* __restrict__ W, unsigned short* __restrict__ Bf,
                             int* __restrict__ cnt, float* __restrict__ hgs,
                             int* __restrict__ ovfc) {
    int idx = blockIdx.x * 256 + threadIdx.x;
    if (idx < NCT * 4 * 64) {
        int lane = idx & 63;
        int kc = (idx >> 6) & 3;
        int ct = idx >> 8;
        int col = ct * 16 + (lane & 15);
        int k0 = kc * 32 + (lane >> 4) * 8;
        unsigned short* outp = Bf + (size_t)idx * 8;
        #pragma unroll
        for (int e = 0; e < 8; ++e) {
            float v = (col < C1) ? W[(k0 + e) * C1 + col] : 0.f;
            outp[e] = f2bf(v);
        }
    }
    for (int i = idx; i < NN * CSTR; i += SCB * 256) cnt[i] = 0;
    if (idx < NB * C2) hgs[idx] = 0.f;
    if (idx == 0) *ovfc = 0;
}

// ---------------- fused front: gemm1 || fc1V || fill+scatter (compute segments first) ----------------
__global__ __launch_bounds__(256) void k_front(const float* __restrict__ feat,
                                               const unsigned short* __restrict__ Bf,
                                               unsigned char* __restrict__ t1f8,
                                               const int* __restrict__ src,
                                               const int* __restrict__ dst,
                                               int* __restrict__ cnt,
                                               unsigned short* __restrict__ epad,
                                               int2* __restrict__ ovf,
                                               int* __restrict__ ovfc,
                                               const float* __restrict__ desc2d,
                                               const float* __restrict__ W1,
                                               float* __restrict__ V) {
    __shared__ float smem[7168];         // 28 KB, shared by gemm1 (sB) and fc1V (S)
    const int tid = threadIdx.x;

    if (blockIdx.x >= GB1 + FCB) {
        // ---- fill + direct scatter: one atomic pass; epad row = one 64B line ----
        int e = (blockIdx.x - GB1 - FCB) * 256 + tid;
        if (e < NE) {
            int d = dst[e], s = src[e];
            int slot = atomicAdd(&cnt[d * CSTR], 1);
            if (slot < SLOT) {
                epad[(size_t)d * SLOT + slot] = (unsigned short)s;
            } else {
                int o = atomicAdd(ovfc, 1);
                if (o < OVFCAP) ovf[o] = make_int2(d, s);
            }
        }
        return;
    }

    if (blockIdx.x < GB1) {
        // ---- gemm1 via MFMA ----
        sh8* sB = (sh8*)smem;            // [NCT][4][64]
        {
            const uint4* srcp = (const uint4*)Bf;
            uint4* dstp = (uint4*)smem;
            for (int i = tid; i < NCT * 4 * 64; i += 256) dstp[i] = srcp[i];
        }
        __syncthreads();
        const int w = tid >> 6, lane = tid & 63;
        const int ri = lane & 15;
        const int kg = lane >> 4;
        int tile = blockIdx.x * 4 + w;
        if (tile < NTILE) {
            const int n = tile * 16 + ri;
            f32x4 acc[NCT];
            #pragma unroll
            for (int ct = 0; ct < NCT; ++ct) acc[ct] = (f32x4){0.f, 0.f, 0.f, 0.f};
            #pragma unroll
            for (int kc = 0; kc < 4; ++kc) {
                const float* ap = feat + (size_t)n * DIN + kc * 32 + kg * 8;
                float4 a0 = *(const float4*)ap;
                float4 a1 = *(const float4*)(ap + 4);
                union { sh8 v; unsigned short u[8]; } af;
                af.u[0] = f2bf(a0.x); af.u[1] = f2bf(a0.y);
                af.u[2] = f2bf(a0.z); af.u[3] = f2bf(a0.w);
                af.u[4] = f2bf(a1.x); af.u[5] = f2bf(a1.y);
                af.u[6] = f2bf(a1.z); af.u[7] = f2bf(a1.w);
                #pragma unroll
                for (int ct = 0; ct < NCT; ++ct)
                    acc[ct] = __builtin_amdgcn_mfma_f32_16x16x32_bf16(
                        af.v, sB[(ct * 4 + kc) * 64 + lane], acc[ct], 0, 0, 0);
            }
            const int rbase = tile * 16 + kg * 4;
            #pragma unroll
            for (int ct = 0; ct < NCT; ++ct) {
                int col = ct * 16 + ri;
                if (col < C1) {
                    #pragma unroll
                    for (int r = 0; r < 4; ++r) {
                        int pk = __builtin_amdgcn_cvt_pk_fp8_f32(acc[ct][r], acc[ct][r], 0, false);
                        t1f8[(size_t)(rbase + r) * PS1 + col] = (unsigned char)(pk & 0xFF);
                    }
                }
            }
        }
        return;
    }

    // ---- fc1V: V[b][i*128+j] = sum_{k<200} desc2d[b][k] * W1[(i*201+k)*128+j] ----
    {
        float (*S)[KDP] = (float(*)[KDP])smem;   // [32][204]
        int fid = blockIdx.x - GB1;              // 0..671
        const int i = fid / 32;
        const int rem = fid % 32;
        const int bt = rem >> 1;
        const int half = rem & 1;
        for (int idx = tid; idx < 32 * 50; idx += 256) {
            int r = idx / 50, c4 = idx % 50;
            *(float4*)&S[r][c4 * 4] =
                *(const float4*)(desc2d + (size_t)(bt * 32 + r) * DD2 + c4 * 4);
        }
        __syncthreads();
        const int c = tid & 31;
        const int rg = tid >> 5;
        float acc[4][2];
        #pragma unroll
        for (int r = 0; r < 4; ++r) { acc[r][0] = 0.f; acc[r][1] = 0.f; }
        const float* Wb = W1 + (size_t)i * (KD * HH1) + half * 64 + c;
        for (int k = 0; k < 200; k += 4) {
            const float* Wk = Wb + (size_t)k * HH1;
            float w0[2], w1[2], w2[2], w3[2];
            #pragma unroll
            for (int m = 0; m < 2; ++m) {
                w0[m] = Wk[32 * m];
                w1[m] = Wk[HH1 + 32 * m];
                w2[m] = Wk[2 * HH1 + 32 * m];
                w3[m] = Wk[3 * HH1 + 32 * m];
            }
            #pragma unroll
            for (int r = 0; r < 4; ++r) {
                float4 a4 = *(const float4*)&S[rg * 4 + r][k];
                #pragma unroll
                for (int m = 0; m < 2; ++m)
                    acc[r][m] += a4.x * w0[m] + a4.y * w1[m] + a4.z * w2[m] + a4.w * w3[m];
            }
        }
        #pragma unroll
        for (int r = 0; r < 4; ++r) {
            int b = bt * 32 + rg * 4 + r;
            float* Vr = V + (size_t)b * NU + i * HH1 + half * 64 + c;
            Vr[0] = acc[r][0];
            Vr[32] = acc[r][1];
        }
    }
}

// ---------------- fused agg1 + gemm2: gather-mean-relu (16 waves) -> LDS -> matvec -> t2b ----------------
// block = 1024 threads = 16 waves; wave w gathers node blockIdx.x*16+w.
__global__ __launch_bounds__(1024) void k_agg1g2(const unsigned char* __restrict__ t1f8,
                                                 const int* __restrict__ cnt,
                                                 const unsigned short* __restrict__ epad,
                                                 const int2* __restrict__ ovf,
                                                 const int* __restrict__ ovfc,
                                                 const float* __restrict__ b1,
                                                 const float* __restrict__ W2,
                                                 unsigned* __restrict__ t2b) {
    __shared__ float sW2[C1 * C2];       // 8 KB
    __shared__ float sh1[16][C1];        // 6.4 KB
    __shared__ float sc[16][C2];         // 1.3 KB
    const int tid = threadIdx.x;
    for (int idx = tid; idx < C1 * C2; idx += 1024) sW2[idx] = W2[idx];
    const int w = tid >> 6, l = tid & 63;
    const int n = blockIdx.x * 16 + w;   // 50000 = 3125*16 exactly
    if (l < 50) {
        const int deg = cnt[n * CSTR];
        const int m = deg < SLOT ? deg : SLOT;
        const unsigned short* ep = epad + (size_t)n * SLOT;
        const int co = 2 * l;
        float acc0 = 0.f, acc1 = 0.f;
        int e = 0;
        for (; e + 7 < m; e += 8) {
            int s0 = ep[e],     s1 = ep[e + 1], s2 = ep[e + 2], s3 = ep[e + 3];
            int s4 = ep[e + 4], s5 = ep[e + 5], s6 = ep[e + 6], s7 = ep[e + 7];
            int u0 = *(const unsigned short*)(t1f8 + (size_t)s0 * PS1 + co);
            int u1 = *(const unsigned short*)(t1f8 + (size_t)s1 * PS1 + co);
            int u2 = *(const unsigned short*)(t1f8 + (size_t)s2 * PS1 + co);
            int u3 = *(const unsigned short*)(t1f8 + (size_t)s3 * PS1 + co);
            int u4 = *(const unsigned short*)(t1f8 + (size_t)s4 * PS1 + co);
            int u5 = *(const unsigned short*)(t1f8 + (size_t)s5 * PS1 + co);
            int u6 = *(const unsigned short*)(t1f8 + (size_t)s6 * PS1 + co);
            int u7 = *(const unsigned short*)(t1f8 + (size_t)s7 * PS1 + co);
            acc0 += __builtin_amdgcn_cvt_f32_fp8(u0, 0); acc1 += __builtin_amdgcn_cvt_f32_fp8(u0, 1);
            acc0 += __builtin_amdgcn_cvt_f32_fp8(u1, 0); acc1 += __builtin_amdgcn_cvt_f32_fp8(u1, 1);
            acc0 += __builtin_amdgcn_cvt_f32_fp8(u2, 0); acc1 += __builtin_amdgcn_cvt_f32_fp8(u2, 1);
            acc0 += __builtin_amdgcn_cvt_f32_fp8(u3, 0); acc1 += __builtin_amdgcn_cvt_f32_fp8(u3, 1);
            acc0 += __builtin_amdgcn_cvt_f32_fp8(u4, 0); acc1 += __builtin_amdgcn_cvt_f32_fp8(u4, 1);
            acc0 += __builtin_amdgcn_cvt_f32_fp8(u5, 0); acc1 += __builtin_amdgcn_cvt_f32_fp8(u5, 1);
            acc0 += __builtin_amdgcn_cvt_f32_fp8(u6, 0); acc1 += __builtin_amdgcn_cvt_f32_fp8(u6, 1);
            acc0 += __builtin_amdgcn_cvt_f32_fp8(u7, 0); acc1 += __builtin_amdgcn_cvt_f32_fp8(u7, 1);
        }
        for (; e < m; ++e) {
            int u = *(const unsigned short*)(t1f8 + (size_t)ep[e] * PS1 + co);
            acc0 += __builtin_amdgcn_cvt_f32_fp8(u, 0);
            acc1 += __builtin_amdgcn_cvt_f32_fp8(u, 1);
        }
        if (deg > SLOT) {
            int novf = *ovfc; novf = novf < OVFCAP ? novf : OVFCAP;
            for (int j2 = 0; j2 < novf; ++j2) {
                int2 p = ovf[j2];
                if (p.x == n) {
                    int u = *(const unsigned short*)(t1f8 + (size_t)p.y * PS1 + co);
                    acc0 += __builtin_amdgcn_cvt_f32_fp8(u, 0);
                    acc1 += __builtin_amdgcn_cvt_f32_fp8(u, 1);
                }
            }
        }
        float d = (float)(deg > 0 ? deg : 1);
        sh1[w][2 * l]     = fmaxf(acc0 / d + b1[2 * l], 0.f);
        sh1[w][2 * l + 1] = fmaxf(acc1 / d + b1[2 * l + 1], 0.f);
    }
    __syncthreads();
    if (tid < 16 * C2) {
        int ln = tid / C2, j = tid % C2;
        float acc = 0.f;
        #pragma unroll 4
        for (int k = 0; k < C1; ++k) acc += sh1[ln][k] * sW2[k * C2 + j];
        sc[ln][j] = acc;
    }
    __syncthreads();
    if (tid < 16 * 10) {
        int r = tid / 10, jp = tid % 10;
        t2b[(size_t)(blockIdx.x * 16 + r) * 10 + jp] =
            (unsigned)f2bf(sc[r][2 * jp]) | ((unsigned)f2bf(sc[r][2 * jp + 1]) << 16);
    }
}

// ---------------- agg2 (padded-slot mean+bias+relu) + graph pool (atomic) ----------------
__global__ void k_agg2p(const unsigned* __restrict__ t2b, const int* __restrict__ cnt,
                        const unsigned short* __restrict__ epad, const int2* __restrict__ ovf,
                        const int* __restrict__ ovfc, const float* __restrict__ bias,
                        const int* __restrict__ gid, float* __restrict__ hgs) {
    int ln = threadIdx.x / C2, c = threadIdx.x % C2;
    if (ln >= 12) return;
    int n = blockIdx.x * 12 + ln;
    if (n >= NN) return;
    const int deg = cnt[n * CSTR];
    const int m = deg < SLOT ? deg : SLOT;
    const unsigned short* ep = epad + (size_t)n * SLOT;
    const int jp = c >> 1, hi = c & 1;
    float acc = 0.f;
    int e = 0;
    for (; e + 3 < m; e += 4) {
        int s0 = ep[e], s1 = ep[e + 1], s2 = ep[e + 2], s3 = ep[e + 3];
        unsigned u0 = t2b[(size_t)s0 * 10 + jp];
        unsigned u1 = t2b[(size_t)s1 * 10 + jp];
        unsigned u2 = t2b[(size_t)s2 * 10 + jp];
        unsigned u3 = t2b[(size_t)s3 * 10 + jp];
        acc += hi ? bf_hi(u0) : bf_lo(u0);
        acc += hi ? bf_hi(u1) : bf_lo(u1);
        acc += hi ? bf_hi(u2) : bf_lo(u2);
        acc += hi ? bf_hi(u3) : bf_lo(u3);
    }
    for (; e < m; ++e) {
        unsigned u = t2b[(size_t)ep[e] * 10 + jp];
        acc += hi ? bf_hi(u) : bf_lo(u);
    }
    if (deg > SLOT) {
        int novf = *ovfc; novf = novf < OVFCAP ? novf : OVFCAP;
        for (int j2 = 0; j2 < novf; ++j2) {
            int2 p = ovf[j2];
            if (p.x == n) {
                unsigned u = t2b[(size_t)p.y * 10 + jp];
                acc += hi ? bf_hi(u) : bf_lo(u);
            }
        }
    }
    float d = (float)(deg > 0 ? deg : 1);
    float v = acc / d + bias[c];
    v = v > 0.f ? v : 0.f;
    atomicAdd(&hgs[gid[n] * C2 + c], v);
}

// ---------------- merged per-graph tail: hg div + attn head + fc1b (o1 write) ----------------
__global__ __launch_bounds__(128) void k_hfc1(const float* __restrict__ hgs,
                                              const int* __restrict__ gid,
                                              const float* __restrict__ desc2d,
                                              const float* __restrict__ pgW,
                                              const float* __restrict__ pgb,
                                              const float* __restrict__ p2W,
                                              const float* __restrict__ p2b,
                                              const float* __restrict__ W2,
                                              const float* __restrict__ V,
                                              const float* __restrict__ W1,
                                              float* __restrict__ o1) {
    __shared__ float shg[C2];
    __shared__ float sg[DHH];
    __shared__ float sa;
    const int b = blockIdx.x, tid = threadIdx.x;
    if (tid < C2) {
        int lo = 0, hi = NN;
        while (lo < hi) { int m = (lo + hi) >> 1; if (gid[m] < b) lo = m + 1; else hi = m; }
        int lo2 = lo, hi2 = NN;
        while (lo2 < hi2) { int m = (lo2 + hi2) >> 1; if (gid[m] < b + 1) lo2 = m + 1; else hi2 = m; }
        float dcnt = (float)(lo2 - lo);
        if (dcnt < 1.f) dcnt = 1.f;
        shg[tid] = hgs[b * C2 + tid] / dcnt;
    }
    __syncthreads();
    float hdj = 0.f;
    if (tid < DHH) {
        float hgj = pgb[tid];
        #pragma unroll
        for (int k = 0; k < C2; ++k) hgj += shg[k] * pgW[k * DHH + tid];
        hdj = p2b[tid];
        #pragma unroll 4
        for (int k = 0; k < DD2; ++k) hdj += desc2d[b * DD2 + k] * p2W[k * DHH + tid];
        sg[tid] = hgj;
    }
    __syncthreads();
    if (tid < DHH) {
        float tj = 0.f;
        #pragma unroll 4
        for (int k = 0; k < DHH; ++k) tj += sg[k] * W2[k * DHH + tid];
        float v = tj * hdj;
        #pragma unroll
        for (int off = 32; off; off >>= 1) v += __shfl_xor(v, off, 64);
        if (tid == 0) sa = 1.f / (1.f + expf(-v));
    }
    __syncthreads();
    const int j = tid;   // 0..127
    const float* Vb = V + (size_t)b * NU + j;
    const float* WL = W1 + (size_t)200 * HH1 + j;
    float sv = Vb[20 * HH1];
    float sw = WL[(size_t)20 * KD * HH1];
    #pragma unroll
    for (int i = 0; i < 20; ++i) {
        float h = shg[i];
        sv += h * Vb[i * HH1];
        sw += h * WL[(size_t)i * KD * HH1];
    }
    o1[b * HH1 + j] = sa * sv + sw;
}

// ---------------- fc2 with in-block bn1 stats ----------------
__global__ __launch_bounds__(128) void k_fc2s(const float* __restrict__ o1,
                                              const float* __restrict__ g,
                                              const float* __restrict__ beta,
                                              const float* __restrict__ W,
                                              float* __restrict__ o2) {
    __shared__ float r[HH1];
    __shared__ float part[4][HH2];
    const int tid = threadIdx.x;   // 128
    float s = 0.f, s2 = 0.f;
    for (int b = 0; b < NB; ++b) {
        float v = o1[b * HH1 + tid];
        s += v; s2 += v * v;
    }
    float mu = s / NB;
    float rstd = rsqrtf(s2 / NB - mu * mu + 1e-5f);
    float scale = rstd * g[tid];
    float shift = beta[tid] - mu * scale;
    const int m = tid & 31, p = tid >> 5;
    for (int q = 0; q < 4; ++q) {
        int b = blockIdx.x * 4 + q;
        float v = o1[b * HH1 + tid];
        __syncthreads();
        r[tid] = fmaxf(v * scale + shift, 0.f);
        __syncthreads();
        float acc = 0.f;
        #pragma unroll 4
        for (int j = p * 32; j < p * 32 + 32; ++j) acc += r[j] * W[j * HH2 + m];
        part[p][m] = acc;
        __syncthreads();
        if (tid < HH2) o2[b * HH2 + tid] = part[0][tid] + part[1][tid] + part[2][tid] + part[3][tid];
    }
}

// ---------------- final: in-block bn2 stats + relu + fc3 ----------------
__global__ __launch_bounds__(512) void k_finals(const float* __restrict__ o2,
                                                const float* __restrict__ g,
                                                const float* __restrict__ beta,
                                                const float* __restrict__ W3,
                                                const float* __restrict__ b3,
                                                float* __restrict__ out) {
    __shared__ float ps[16][HH2], ps2[16][HH2];
    __shared__ float sscale[HH2], sshift[HH2];
    const int tid = threadIdx.x;    // 512
    const int gq = tid >> 5, m = tid & 31;
    float s = 0.f, s2 = 0.f;
    for (int rr = 0; rr < 32; ++rr) {
        float v = o2[(gq * 32 + rr) * HH2 + m];
        s += v; s2 += v * v;
    }
    ps[gq][m] = s; ps2[gq][m] = s2;
    __syncthreads();
    if (tid < HH2) {
        float ts = 0.f, ts2 = 0.f;
        #pragma unroll
        for (int q = 0; q < 16; ++q) { ts += ps[q][tid]; ts2 += ps2[q][tid]; }
        float mu = ts / NB;
        float rstd = rsqrtf(ts2 / NB - mu * mu + 1e-5f);
        float scale = rstd * g[tid];
        sscale[tid] = scale;
        sshift[tid] = beta[tid] - mu * scale;
    }
    __syncthreads();
    float acc = b3[0];
    #pragma unroll 4
    for (int mm = 0; mm < HH2; ++mm) {
        float v = o2[tid * HH2 + mm];
        acc += fmaxf(v * sscale[mm] + sshift[mm], 0.f) * W3[mm];
    }
    out[tid] = acc;
}

extern "C" void kernel_launch(void* const* d_in, const int* in_sizes, int n_in,
                              void* d_out, int out_size, void* d_ws, size_t ws_size,
                              hipStream_t stream) {
    const float* feat   = (const float*)d_in[0];
    const float* desc2d = (const float*)d_in[1];
    const float* gc1W = (const float*)d_in[3];
    const float* gc1b = (const float*)d_in[4];
    const float* gc2W = (const float*)d_in[5];
    const float* gc2b = (const float*)d_in[6];
    const float* pgW  = (const float*)d_in[7];
    const float* pgb  = (const float*)d_in[8];
    const float* p2W  = (const float*)d_in[9];
    const float* p2b  = (const float*)d_in[10];
    const float* W2   = (const float*)d_in[11];
    const float* fc1W = (const float*)d_in[12];
    const float* fc2W = (const float*)d_in[14];
    const float* fc3W = (const float*)d_in[16];
    const float* fc3b = (const float*)d_in[17];
    const float* bn1g = (const float*)d_in[18];
    const float* bn1b = (const float*)d_in[19];
    const float* bn2g = (const float*)d_in[20];
    const float* bn2b = (const float*)d_in[21];
    const int* src = (const int*)d_in[22];
    const int* dst = (const int*)d_in[23];
    const int* gid = (const int*)d_in[24];
    float* out = (float*)d_out;

    char* ws = (char*)d_ws;
    size_t off = 0;
    auto alloc = [&](size_t nb) {
        void* p = ws + off;
        off = (off + nb + 255) & ~(size_t)255;
        return p;
    };
    unsigned char* t1f8 = (unsigned char*)alloc((size_t)NN * PS1);   // 6.4 MB fp8
    unsigned* t2b = (unsigned*)alloc((size_t)NN * 10 * 4);           // 2 MB packed bf16
    int* cnt_in  = (int*)alloc((size_t)NN * CSTR * 4);               // 3.2 MB line-padded
    unsigned short* epad = (unsigned short*)alloc((size_t)NN * SLOT * 2);  // 3.2 MB u16
    int2* ovf    = (int2*)alloc((size_t)OVFCAP * 8);
    int* ovfc    = (int*)alloc(256);
    unsigned short* Bf = (unsigned short*)alloc((size_t)NCT * 4 * 64 * 16);  // 28 KB
    float* V     = (float*)alloc((size_t)NB * NU * 4);               // 5.5 MB
    float* hgs   = (float*)alloc((size_t)NB * C2 * 4);
    float* o1    = (float*)alloc((size_t)NB * HH1 * 4);
    float* o2    = (float*)alloc((size_t)NB * HH2 * 4);

    k_packB_init<<<SCB, 256, 0, stream>>>(gc1W, Bf, cnt_in, hgs, ovfc);
    k_front<<<GB1 + FCB + FPB, 256, 0, stream>>>(feat, Bf, t1f8, src, dst, cnt_in,
                                                 epad, ovf, ovfc, desc2d, fc1W, V);

    k_agg1g2<<<NTILE, 1024, 0, stream>>>(t1f8, cnt_in, epad, ovf, ovfc, gc1b, gc2W, t2b);
    k_agg2p<<<(NN + 11) / 12, 256, 0, stream>>>(t2b, cnt_in, epad, ovf, ovfc, gc2b, gid, hgs);

    k_hfc1<<<NB, 128, 0, stream>>>(hgs, gid, desc2d, pgW, pgb, p2W, p2b, W2, V, fc1W, o1);
    k_fc2s<<<NB / 4, 128, 0, stream>>>(o1, bn1g, bn1b, fc2W, o2);
    k_finals<<<1, 512, 0, stream>>>(o2, bn2g, bn2b, fc3W, fc3b, out);
}